// Round 14
// baseline (101.276 us; speedup 1.0000x reference)
//
#include <hip/hip_runtime.h>

#define B_ 8
#define N_ 512
#define D_ 256
#define H_ 8
#define HD_ 32
#define E_ 8192
#define EA_ 32

#define LOG1EM6 -13.815510557964274f
#define SCALE 0.17677669529663687f

typedef _Float16 half8 __attribute__((ext_vector_type(8)));
typedef _Float16 half4t __attribute__((ext_vector_type(4)));
typedef __fp16 fp16x2 __attribute__((ext_vector_type(2)));
typedef float f32x16 __attribute__((ext_vector_type(16)));

// ---------------------------------------------------------------------------
// Kernel 1: prep.
//  blocks 0..511 : packT[b][v][u] = f16bits(adj[u][v])<<16 | 0
//                  (transpose pass IS the sentinel fill — no separate memset)
//  blocks 512..559: W (256x768) -> Wt[col][k] f16
// ---------------------------------------------------------------------------
__global__ __launch_bounds__(256) void prep_kernel(
    int* __restrict__ packT, const float* __restrict__ W,
    _Float16* __restrict__ Wt, const float* __restrict__ adj)
{
    __shared__ float t[64][65];
    const int blk = blockIdx.x;
    const int r  = threadIdx.x >> 4;      // 0..15
    const int c4 = (threadIdx.x & 15) * 4;

    if (blk < 512) {
        // adj transpose -> packed high-half f16 bits
        const int b = blk >> 6, vt = (blk >> 3) & 7, ut = blk & 7;
        const int u0 = ut * 64, v0 = vt * 64;
        const float* src = adj + ((size_t)b * N_ + u0) * N_ + v0;
#pragma unroll
        for (int it = 0; it < 4; it++) {
            int rr = r + it * 16;
            float4 v = *(const float4*)&src[rr * N_ + c4];
            t[rr][c4 + 0] = v.x; t[rr][c4 + 1] = v.y;
            t[rr][c4 + 2] = v.z; t[rr][c4 + 3] = v.w;
        }
        __syncthreads();
        int* dst = packT + ((size_t)b * N_ + v0) * N_ + u0;
#pragma unroll
        for (int it = 0; it < 4; it++) {
            int rr = r + it * 16;
            int4 pv;
            union { _Float16 f; unsigned short s; } cc;
            cc.f = (_Float16)t[c4 + 0][rr]; pv.x = ((int)cc.s) << 16;
            cc.f = (_Float16)t[c4 + 1][rr]; pv.y = ((int)cc.s) << 16;
            cc.f = (_Float16)t[c4 + 2][rr]; pv.z = ((int)cc.s) << 16;
            cc.f = (_Float16)t[c4 + 3][rr]; pv.w = ((int)cc.s) << 16;
            *(int4*)&dst[rr * N_ + c4] = pv;
        }
    } else {
        // W -> Wt[col][k] f16
        const int ti = blk - 512;         // 0..47
        const int k0 = (ti / 12) * 64;
        const int n0 = (ti % 12) * 64;
        const float* src = W + (size_t)k0 * 768 + n0;
#pragma unroll
        for (int it = 0; it < 4; it++) {
            int rr = r + it * 16;
            float4 v = *(const float4*)&src[rr * 768 + c4];
            t[rr][c4 + 0] = v.x; t[rr][c4 + 1] = v.y;
            t[rr][c4 + 2] = v.z; t[rr][c4 + 3] = v.w;
        }
        __syncthreads();
        _Float16* dst = Wt + (size_t)n0 * 256 + k0;
#pragma unroll
        for (int it = 0; it < 4; it++) {
            int rr = r + it * 16;
            half4t hv;
#pragma unroll
            for (int kk = 0; kk < 4; kk++) hv[kk] = (_Float16)t[c4 + kk][rr];
            *(half4t*)&dst[rr * 256 + c4] = hv;
        }
    }
}

// ---------------------------------------------------------------------------
// Kernel 2: mid = qkv MFMA GEMM (blocks 0..767) + edge kernel (768..1023).
// qkv emits MFMA-ready fragments (r13-verified fragment identity chain).
// edge: atomicMax(packT, adjbits<<16 | e+1) — same adjbits as prep wrote
// (identical f16 conversion of the identical adj element), so the int max
// resolves on e+1 = numpy last-write-wins.
// ---------------------------------------------------------------------------
__global__ __launch_bounds__(256) void mid_kernel(
    const float* __restrict__ x, const _Float16* __restrict__ Wt,
    const float* __restrict__ bias,
    _Float16* __restrict__ Qf, _Float16* __restrict__ Kf,
    _Float16* __restrict__ Vf,
    const float* __restrict__ edge_attr, const int* __restrict__ edge_index,
    const float* __restrict__ adj,
    const float* __restrict__ ds_W, const float* __restrict__ ds_b,
    const float* __restrict__ dw_W, const float* __restrict__ dw_b,
    const float* __restrict__ shifts, const float* __restrict__ widths,
    float* __restrict__ mlog, int* __restrict__ packT)
{
    extern __shared__ char lds[];
    const int tid = threadIdx.x;
    const int blk = blockIdx.x;

    if (blk < 768) {
        const int m0 = (blk / 12) * 64;
        const int n0 = (blk % 12) * 64;

#pragma unroll
        for (int it = 0; it < 16; it++) {
            int g   = tid + it * 256;
            int row = g & 63, k4 = g >> 6;
            float4 v = *(const float4*)&x[(size_t)(m0 + row) * 256 + k4 * 4];
            union { _Float16 h[4]; uint2 u; } c;
            c.h[0] = (_Float16)v.x; c.h[1] = (_Float16)v.y;
            c.h[2] = (_Float16)v.z; c.h[3] = (_Float16)v.w;
            int ks = k4 >> 2, hb = (k4 >> 1) & 1, lhi = k4 & 1;
            int off = (((row >> 5) * 16 + ks) << 10) +
                      ((lhi * 32 + (row & 31)) << 4) + hb * 8;
            *(uint2*)(lds + off) = c.u;
        }
#pragma unroll
        for (int it = 0; it < 16; it++) {
            int g   = tid + it * 256;
            int col = g & 63, k4 = g >> 6;
            uint2 v = *(const uint2*)&Wt[(size_t)(n0 + col) * 256 + k4 * 4];
            int ks = k4 >> 2, hb = (k4 >> 1) & 1, lhi = k4 & 1;
            int off = 32768 + (((col >> 5) * 16 + ks) << 10) +
                      ((lhi * 32 + (col & 31)) << 4) + hb * 8;
            *(uint2*)(lds + off) = v;
        }
        __syncthreads();

        const int wv = tid >> 6, lane = tid & 63, hi = lane >> 5;
        const int rb = wv & 1, cb = wv >> 1;
        const int c_base = n0 + cb * 32;
        const int which  = c_base >> 8;
        const int h      = (c_base >> 5) & 7;
        const int b      = m0 >> 9;
        const int ut     = ((m0 & 511) >> 5) + rb;

        f32x16 acc;
#pragma unroll
        for (int r = 0; r < 16; r++) acc[r] = 0.0f;

        if (which < 2) {
#pragma unroll
            for (int ks = 0; ks < 16; ks++) {
                half8 af = *(const half8*)(lds + 32768 + (((cb * 16 + ks) << 10)) + lane * 16);
                half8 bf = *(const half8*)(lds + (((rb * 16 + ks) << 10)) + lane * 16);
                acc = __builtin_amdgcn_mfma_f32_32x32x16_f16(af, bf, acc, 0, 0, 0);
            }
            _Float16* dst = (which == 0) ? Qf : Kf;
            const float sc = (which == 0) ? SCALE : 1.0f;
            size_t pb = (((size_t)(b * H_ + h) * 16 + ut) * 2) * 1024;
#pragma unroll
            for (int kh = 0; kh < 2; kh++) {
                union { _Float16 h[8]; int4 q; } fr;
#pragma unroll
                for (int j = 0; j < 8; j++) {
                    int r = kh * 8 + j;
                    int hd = (r & 3) + 8 * (r >> 2) + 4 * hi;
                    fr.h[j] = (_Float16)((acc[r] + bias[c_base + hd]) * sc);
                }
                *(int4*)((char*)dst + pb + kh * 1024 + lane * 16) = fr.q;
            }
        } else {
#pragma unroll
            for (int ks = 0; ks < 16; ks++) {
                half8 af = *(const half8*)(lds + (((rb * 16 + ks) << 10)) + lane * 16);
                half8 bf = *(const half8*)(lds + 32768 + (((cb * 16 + ks) << 10)) + lane * 16);
                acc = __builtin_amdgcn_mfma_f32_32x32x16_f16(af, bf, acc, 0, 0, 0);
            }
            const float bcol = bias[c_base + (lane & 31)];
            size_t pb = (((size_t)(b * H_ + h) * 16 + ut) * 2) * 1024;
#pragma unroll
            for (int kh = 0; kh < 2; kh++) {
                union { _Float16 h[8]; int4 q; } fr;
#pragma unroll
                for (int j = 0; j < 8; j++)
                    fr.h[j] = (_Float16)(acc[kh * 8 + j] + bcol);
                *(int4*)((char*)Vf + pb + kh * 1024 + lane * 16) = fr.q;
            }
        }
        return;
    }

    // ---------------- edge kernel ----------------
    float* ea  = (float*)lds;
    float* dsW = ea + 256 * 33;
    float* dwW = dsW + 256;
    const int eb = blk - 768;
    const int b  = eb >> 5;
    const int e0 = (eb & 31) * 256;

    const float* eabase = edge_attr + ((size_t)b * E_ + e0) * EA_;
#pragma unroll
    for (int it = 0; it < 32; it++) {
        int i = tid + it * 256;
        ea[(i >> 5) * 33 + (i & 31)] = eabase[i];
    }
    dsW[tid] = ds_W[tid];
    dwW[tid] = dw_W[tid];
    __syncthreads();

    const int e  = e0 + tid;
    const int eu = edge_index[(size_t)b * 2 * E_ + e];
    const int ev = edge_index[(size_t)b * 2 * E_ + E_ + e];
    const float d = adj[((size_t)b * N_ + eu) * N_ + ev];

    float ds[8], dw[8];
#pragma unroll
    for (int h = 0; h < 8; h++) { ds[h] = ds_b[h]; dw[h] = dw_b[h]; }
#pragma unroll
    for (int k = 0; k < 32; k++) {
        float a = ea[tid * 33 + k];
#pragma unroll
        for (int h = 0; h < 8; h++) {
            ds[h] += a * dsW[k * 8 + h];
            dw[h] += a * dwW[k * 8 + h];
        }
    }
#pragma unroll
    for (int h = 0; h < 8; h++) {
        float ms = shifts[h] + ds[h];
        float mw = widths[h] + dw[h];
        float t  = d - ms;
        float ml = fmaxf(-(t * t) / (2.0f * mw * mw + 1e-6f), LOG1EM6);
        mlog[((size_t)(b * H_ + h)) * E_ + e] = ml;
    }
    union { _Float16 f; unsigned short s; } ab;
    ab.f = (_Float16)d;                       // same conversion as prep
    atomicMax(&packT[((size_t)b * N_ + ev) * N_ + eu],
              (((int)ab.s) << 16) | (e + 1));
}

// ---------------------------------------------------------------------------
// helpers
// ---------------------------------------------------------------------------
__device__ __forceinline__ unsigned pkf16(float x, float y)
{
    fp16x2 v = __builtin_amdgcn_cvt_pkrtz(x, y);
    union { fp16x2 h; unsigned u; } c; c.h = v; return c.u;
}

__device__ __forceinline__ half8 pack_pfrag(const float* p)
{
    union { unsigned u[4]; half8 h; } r;
    r.u[0] = pkf16(p[0], p[1]);
    r.u[1] = pkf16(p[2], p[3]);
    r.u[2] = pkf16(p[4], p[5]);
    r.u[3] = pkf16(p[6], p[7]);
    return r.h;
}

__device__ __forceinline__ float av_from_pack(int pk)
{
    union { unsigned short s; _Float16 f; } cc;
    cc.s = (unsigned short)(((unsigned)pk) >> 16);
    return (float)cc.f;
}

// ---------------------------------------------------------------------------
// Kernel 3: MFMA attention, LDS-free, SOFTWARE-PIPELINED (depth 1):
// tile vt+1's K/V frags + 16 pack-words are issued before computing tile vt,
// giving loads a full iteration of latency cover at 1 wave/SIMD occupancy.
// Logic identical to the r10/r13-verified kernel.
// ---------------------------------------------------------------------------
__global__ __launch_bounds__(64, 1) void attn_kernel(
    const _Float16* __restrict__ Qf, const _Float16* __restrict__ Kf,
    const _Float16* __restrict__ Vf, const int* __restrict__ packT,
    const float* __restrict__ mlog,
    const float* __restrict__ shifts, const float* __restrict__ widths,
    const float* __restrict__ slw_arr, float* __restrict__ out)
{
    const int bid  = blockIdx.x;          // b*128 + h*16 + ut
    const int b    = bid >> 7;
    const int h    = (bid >> 4) & 7;
    const int ut   = bid & 15;
    const int lane = threadIdx.x;
    const int hi   = lane >> 5;
    const int u0w  = ut * 32;

    const size_t panel = ((size_t)(b * H_ + h) * 16) * 2048; // bytes
    const char* Kp = (const char*)Kf + panel;
    const char* Vp = (const char*)Vf + panel;
    const char* Qp = (const char*)Qf + panel;

    half8 qf0 = *(const half8*)(Qp + (ut * 2 + 0) * 1024 + lane * 16);
    half8 qf1 = *(const half8*)(Qp + (ut * 2 + 1) * 1024 + lane * 16);

    const float s_h   = shifts[h];
    const float w_h   = widths[h];
    const float inv2w = 1.0f / (2.0f * w_h * w_h + 1e-6f);
    const float slw   = slw_arr[h];
    const float* mlg  = mlog + (size_t)(b * H_ + h) * E_;
    const int ucol    = u0w + (lane & 31);
    const int* prow   = packT + (size_t)b * N_ * N_ + ucol;

    f32x16 Oacc;
#pragma unroll
    for (int r = 0; r < 16; r++) Oacc[r] = 0.0f;
    float m = -1e30f, ssum = 0.0f;

    // prologue: tile 0 loads
    half8 ka0 = *(const half8*)(Kp + 0 * 1024 + lane * 16);
    half8 ka1 = *(const half8*)(Kp + 1 * 1024 + lane * 16);
    half8 vb0 = *(const half8*)(Vp + 0 * 1024 + lane * 16);
    half8 vb1 = *(const half8*)(Vp + 1 * 1024 + lane * 16);
    int pk[16];
    {
        const int vbase = 4 * hi;
#pragma unroll
        for (int r = 0; r < 16; r++) {
            int vg = vbase + (r & 3) + 8 * (r >> 2);
            pk[r] = prow[(size_t)vg * N_];
        }
    }

    for (int vt = 0; vt < 16; vt++) {
        // issue next tile's loads (cover ~1 iteration of latency)
        half8 nka0, nka1, nvb0, nvb1;
        int npk[16];
        if (vt < 15) {
            nka0 = *(const half8*)(Kp + ((vt + 1) * 2 + 0) * 1024 + lane * 16);
            nka1 = *(const half8*)(Kp + ((vt + 1) * 2 + 1) * 1024 + lane * 16);
            nvb0 = *(const half8*)(Vp + ((vt + 1) * 2 + 0) * 1024 + lane * 16);
            nvb1 = *(const half8*)(Vp + ((vt + 1) * 2 + 1) * 1024 + lane * 16);
            const int nvbase = (vt + 1) * 32 + 4 * hi;
#pragma unroll
            for (int r = 0; r < 16; r++) {
                int vg = nvbase + (r & 3) + 8 * (r >> 2);
                npk[r] = prow[(size_t)vg * N_];
            }
        }

        // QK^T tile (S^T)
        f32x16 C;
#pragma unroll
        for (int r = 0; r < 16; r++) C[r] = 0.0f;
        C = __builtin_amdgcn_mfma_f32_32x32x16_f16(ka0, qf0, C, 0, 0, 0);
        C = __builtin_amdgcn_mfma_f32_32x32x16_f16(ka1, qf1, C, 0, 0, 0);

        // adjust + tile max
        float p[16];
        float pmax = -1e30f;
        const int vbase = vt * 32 + 4 * hi;
#pragma unroll
        for (int r = 0; r < 16; r++) {
            int vg  = vbase + (r & 3) + 8 * (r >> 2);
            int pkr = pk[r];
            int sv  = (pkr & 0xffff) - 1;
            float av = av_from_pack(pkr);
            float ml = mlg[sv < 0 ? 0 : sv];
            float t  = av - s_h;
            float bl = fmaxf(-(t * t) * inv2w, LOG1EM6);
            float sc = C[r] + (sv >= 0 ? ml : bl);
            if (vg == ucol) sc += slw;
            p[r] = sc;
            pmax = fmaxf(pmax, sc);
        }
        pmax = fmaxf(pmax, __shfl_xor(pmax, 32, 64));

        // defer-max online update (T13, THR=8)
        if (!__all(pmax - m <= 8.0f)) {
            float mnew = fmaxf(m, pmax);
            float scl  = __expf(m - mnew);
#pragma unroll
            for (int r = 0; r < 16; r++) {
                int ur = (r & 3) + 8 * (r >> 2) + 4 * hi;
                Oacc[r] *= __shfl(scl, ur, 64);
            }
            ssum *= scl;
            m = mnew;
        }

#pragma unroll
        for (int r = 0; r < 16; r++) {
            p[r] = __expf(p[r] - m);
            ssum += p[r];
        }

        half8 pa0 = pack_pfrag(&p[0]);
        half8 pa1 = pack_pfrag(&p[8]);
        Oacc = __builtin_amdgcn_mfma_f32_32x32x16_f16(pa0, vb0, Oacc, 0, 0, 0);
        Oacc = __builtin_amdgcn_mfma_f32_32x32x16_f16(pa1, vb1, Oacc, 0, 0, 0);

        // rotate pipeline regs
        ka0 = nka0; ka1 = nka1; vb0 = nvb0; vb1 = nvb1;
#pragma unroll
        for (int r = 0; r < 16; r++) pk[r] = npk[r];
    }

    float stot = ssum + __shfl_xor(ssum, 32, 64);
    float rs = 1.0f / stot;
#pragma unroll
    for (int r = 0; r < 16; r++) {
        int ur = (r & 3) + 8 * (r >> 2) + 4 * hi;
        float o = Oacc[r] * __shfl(rs, ur, 64);
        int ug = u0w + ur;
        out[((size_t)(b * N_ + ug)) * D_ + h * HD_ + (lane & 31)] = o;
    }
}

// ---------------------------------------------------------------------------
extern "C" void kernel_launch(void* const* d_in, const int* in_sizes, int n_in,
                              void* d_out, int out_size, void* d_ws, size_t ws_size,
                              hipStream_t stream)
{
    const float* x          = (const float*)d_in[0];
    const float* adj        = (const float*)d_in[1];
    const int*   edge_index = (const int*)d_in[2];
    const float* edge_attr  = (const float*)d_in[3];
    const float* qkv_W      = (const float*)d_in[6];
    const float* qkv_b      = (const float*)d_in[7];
    const float* ds_W       = (const float*)d_in[12];
    const float* ds_b       = (const float*)d_in[13];
    const float* dw_W       = (const float*)d_in[14];
    const float* dw_b       = (const float*)d_in[15];
    const float* shifts     = (const float*)d_in[16];
    const float* widths     = (const float*)d_in[17];
    const float* slw        = (const float*)d_in[18];
    float* out = (float*)d_out;

    // workspace layout (~16.4MB)
    _Float16* Qf   = (_Float16*)d_ws;                      // 2MB
    _Float16* Kf   = Qf + (size_t)B_ * H_ * N_ * HD_;      // 2MB
    _Float16* Vf   = Kf + (size_t)B_ * H_ * N_ * HD_;      // 2MB
    float*    mlog = (float*)(Vf + (size_t)B_ * H_ * N_ * HD_);    // 2MB
    int*      packT = (int*)(mlog + (size_t)B_ * H_ * E_); // 8MB
    _Float16* Wt   = (_Float16*)(packT + (size_t)B_ * N_ * N_);    // 384KB

    prep_kernel<<<dim3(560), 256, 0, stream>>>(packT, qkv_W, Wt, adj);

    hipFuncSetAttribute((const void*)mid_kernel,
                        hipFuncAttributeMaxDynamicSharedMemorySize, 65536);
    mid_kernel<<<dim3(1024), 256, 65536, stream>>>(
        x, Wt, qkv_b, Qf, Kf, Vf,
        edge_attr, edge_index, adj,
        ds_W, ds_b, dw_W, dw_b, shifts, widths, mlog, packT);

    attn_kernel<<<dim3(1024), 64, 0, stream>>>(Qf, Kf, Vf, packT,
                                               mlog, shifts, widths, slw, out);
}

// Round 15
// 62.612 us; speedup vs baseline: 1.6175x; 1.6175x over previous
//
#include <hip/hip_runtime.h>

#define B_ 8
#define N_ 512
#define D_ 256
#define H_ 8
#define HD_ 32
#define E_ 8192
#define EA_ 32

#define LOG1EM6 -13.815510557964274f
#define SCALE 0.17677669529663687f

typedef _Float16 half8 __attribute__((ext_vector_type(8)));
typedef _Float16 half4t __attribute__((ext_vector_type(4)));
typedef __fp16 fp16x2 __attribute__((ext_vector_type(2)));
typedef float f32x16 __attribute__((ext_vector_type(16)));

// ---------------------------------------------------------------------------
// Kernel 1: prep.
//  blocks 0..511 : packT[b][v][u] = f16bits(adj[u][v])<<16 | 0
//                  (transpose pass IS the sentinel fill — no separate memset)
//  blocks 512..559: W (256x768) -> Wt[col][k] f16
// ---------------------------------------------------------------------------
__global__ __launch_bounds__(256) void prep_kernel(
    int* __restrict__ packT, const float* __restrict__ W,
    _Float16* __restrict__ Wt, const float* __restrict__ adj)
{
    __shared__ float t[64][65];
    const int blk = blockIdx.x;
    const int r  = threadIdx.x >> 4;      // 0..15
    const int c4 = (threadIdx.x & 15) * 4;

    if (blk < 512) {
        // adj transpose -> packed high-half f16 bits
        const int b = blk >> 6, vt = (blk >> 3) & 7, ut = blk & 7;
        const int u0 = ut * 64, v0 = vt * 64;
        const float* src = adj + ((size_t)b * N_ + u0) * N_ + v0;
#pragma unroll
        for (int it = 0; it < 4; it++) {
            int rr = r + it * 16;
            float4 v = *(const float4*)&src[rr * N_ + c4];
            t[rr][c4 + 0] = v.x; t[rr][c4 + 1] = v.y;
            t[rr][c4 + 2] = v.z; t[rr][c4 + 3] = v.w;
        }
        __syncthreads();
        int* dst = packT + ((size_t)b * N_ + v0) * N_ + u0;
#pragma unroll
        for (int it = 0; it < 4; it++) {
            int rr = r + it * 16;
            int4 pv;
            union { _Float16 f; unsigned short s; } cc;
            cc.f = (_Float16)t[c4 + 0][rr]; pv.x = ((int)cc.s) << 16;
            cc.f = (_Float16)t[c4 + 1][rr]; pv.y = ((int)cc.s) << 16;
            cc.f = (_Float16)t[c4 + 2][rr]; pv.z = ((int)cc.s) << 16;
            cc.f = (_Float16)t[c4 + 3][rr]; pv.w = ((int)cc.s) << 16;
            *(int4*)&dst[rr * N_ + c4] = pv;
        }
    } else {
        // W -> Wt[col][k] f16
        const int ti = blk - 512;         // 0..47
        const int k0 = (ti / 12) * 64;
        const int n0 = (ti % 12) * 64;
        const float* src = W + (size_t)k0 * 768 + n0;
#pragma unroll
        for (int it = 0; it < 4; it++) {
            int rr = r + it * 16;
            float4 v = *(const float4*)&src[rr * 768 + c4];
            t[rr][c4 + 0] = v.x; t[rr][c4 + 1] = v.y;
            t[rr][c4 + 2] = v.z; t[rr][c4 + 3] = v.w;
        }
        __syncthreads();
        _Float16* dst = Wt + (size_t)n0 * 256 + k0;
#pragma unroll
        for (int it = 0; it < 4; it++) {
            int rr = r + it * 16;
            half4t hv;
#pragma unroll
            for (int kk = 0; kk < 4; kk++) hv[kk] = (_Float16)t[c4 + kk][rr];
            *(half4t*)&dst[rr * 256 + c4] = hv;
        }
    }
}

// ---------------------------------------------------------------------------
// Kernel 2: mid = qkv MFMA GEMM (blocks 0..767) + edge kernel (768..1023).
// qkv emits MFMA-ready fragments (r13-verified fragment identity chain).
// edge: atomicMax(packT, adjbits<<16 | e+1) — same adjbits as prep wrote,
// so the int max resolves on e+1 = numpy last-write-wins.
// ---------------------------------------------------------------------------
__global__ __launch_bounds__(256) void mid_kernel(
    const float* __restrict__ x, const _Float16* __restrict__ Wt,
    const float* __restrict__ bias,
    _Float16* __restrict__ Qf, _Float16* __restrict__ Kf,
    _Float16* __restrict__ Vf,
    const float* __restrict__ edge_attr, const int* __restrict__ edge_index,
    const float* __restrict__ adj,
    const float* __restrict__ ds_W, const float* __restrict__ ds_b,
    const float* __restrict__ dw_W, const float* __restrict__ dw_b,
    const float* __restrict__ shifts, const float* __restrict__ widths,
    float* __restrict__ mlog, int* __restrict__ packT)
{
    extern __shared__ char lds[];
    const int tid = threadIdx.x;
    const int blk = blockIdx.x;

    if (blk < 768) {
        const int m0 = (blk / 12) * 64;
        const int n0 = (blk % 12) * 64;

#pragma unroll
        for (int it = 0; it < 16; it++) {
            int g   = tid + it * 256;
            int row = g & 63, k4 = g >> 6;
            float4 v = *(const float4*)&x[(size_t)(m0 + row) * 256 + k4 * 4];
            union { _Float16 h[4]; uint2 u; } c;
            c.h[0] = (_Float16)v.x; c.h[1] = (_Float16)v.y;
            c.h[2] = (_Float16)v.z; c.h[3] = (_Float16)v.w;
            int ks = k4 >> 2, hb = (k4 >> 1) & 1, lhi = k4 & 1;
            int off = (((row >> 5) * 16 + ks) << 10) +
                      ((lhi * 32 + (row & 31)) << 4) + hb * 8;
            *(uint2*)(lds + off) = c.u;
        }
#pragma unroll
        for (int it = 0; it < 16; it++) {
            int g   = tid + it * 256;
            int col = g & 63, k4 = g >> 6;
            uint2 v = *(const uint2*)&Wt[(size_t)(n0 + col) * 256 + k4 * 4];
            int ks = k4 >> 2, hb = (k4 >> 1) & 1, lhi = k4 & 1;
            int off = 32768 + (((col >> 5) * 16 + ks) << 10) +
                      ((lhi * 32 + (col & 31)) << 4) + hb * 8;
            *(uint2*)(lds + off) = v;
        }
        __syncthreads();

        const int wv = tid >> 6, lane = tid & 63, hi = lane >> 5;
        const int rb = wv & 1, cb = wv >> 1;
        const int c_base = n0 + cb * 32;
        const int which  = c_base >> 8;
        const int h      = (c_base >> 5) & 7;
        const int b      = m0 >> 9;
        const int ut     = ((m0 & 511) >> 5) + rb;

        f32x16 acc;
#pragma unroll
        for (int r = 0; r < 16; r++) acc[r] = 0.0f;

        if (which < 2) {
#pragma unroll
            for (int ks = 0; ks < 16; ks++) {
                half8 af = *(const half8*)(lds + 32768 + (((cb * 16 + ks) << 10)) + lane * 16);
                half8 bf = *(const half8*)(lds + (((rb * 16 + ks) << 10)) + lane * 16);
                acc = __builtin_amdgcn_mfma_f32_32x32x16_f16(af, bf, acc, 0, 0, 0);
            }
            _Float16* dst = (which == 0) ? Qf : Kf;
            const float sc = (which == 0) ? SCALE : 1.0f;
            size_t pb = (((size_t)(b * H_ + h) * 16 + ut) * 2) * 1024;
#pragma unroll
            for (int kh = 0; kh < 2; kh++) {
                union { _Float16 h[8]; int4 q; } fr;
#pragma unroll
                for (int j = 0; j < 8; j++) {
                    int r = kh * 8 + j;
                    int hd = (r & 3) + 8 * (r >> 2) + 4 * hi;
                    fr.h[j] = (_Float16)((acc[r] + bias[c_base + hd]) * sc);
                }
                *(int4*)((char*)dst + pb + kh * 1024 + lane * 16) = fr.q;
            }
        } else {
#pragma unroll
            for (int ks = 0; ks < 16; ks++) {
                half8 af = *(const half8*)(lds + (((rb * 16 + ks) << 10)) + lane * 16);
                half8 bf = *(const half8*)(lds + 32768 + (((cb * 16 + ks) << 10)) + lane * 16);
                acc = __builtin_amdgcn_mfma_f32_32x32x16_f16(af, bf, acc, 0, 0, 0);
            }
            const float bcol = bias[c_base + (lane & 31)];
            size_t pb = (((size_t)(b * H_ + h) * 16 + ut) * 2) * 1024;
#pragma unroll
            for (int kh = 0; kh < 2; kh++) {
                union { _Float16 h[8]; int4 q; } fr;
#pragma unroll
                for (int j = 0; j < 8; j++)
                    fr.h[j] = (_Float16)(acc[kh * 8 + j] + bcol);
                *(int4*)((char*)Vf + pb + kh * 1024 + lane * 16) = fr.q;
            }
        }
        return;
    }

    // ---------------- edge kernel ----------------
    float* ea  = (float*)lds;
    float* dsW = ea + 256 * 33;
    float* dwW = dsW + 256;
    const int eb = blk - 768;
    const int b  = eb >> 5;
    const int e0 = (eb & 31) * 256;

    const float* eabase = edge_attr + ((size_t)b * E_ + e0) * EA_;
#pragma unroll
    for (int it = 0; it < 32; it++) {
        int i = tid + it * 256;
        ea[(i >> 5) * 33 + (i & 31)] = eabase[i];
    }
    dsW[tid] = ds_W[tid];
    dwW[tid] = dw_W[tid];
    __syncthreads();

    const int e  = e0 + tid;
    const int eu = edge_index[(size_t)b * 2 * E_ + e];
    const int ev = edge_index[(size_t)b * 2 * E_ + E_ + e];
    const float d = adj[((size_t)b * N_ + eu) * N_ + ev];

    float ds[8], dw[8];
#pragma unroll
    for (int h = 0; h < 8; h++) { ds[h] = ds_b[h]; dw[h] = dw_b[h]; }
#pragma unroll
    for (int k = 0; k < 32; k++) {
        float a = ea[tid * 33 + k];
#pragma unroll
        for (int h = 0; h < 8; h++) {
            ds[h] += a * dsW[k * 8 + h];
            dw[h] += a * dwW[k * 8 + h];
        }
    }
#pragma unroll
    for (int h = 0; h < 8; h++) {
        float ms = shifts[h] + ds[h];
        float mw = widths[h] + dw[h];
        float t  = d - ms;
        float ml = fmaxf(-(t * t) / (2.0f * mw * mw + 1e-6f), LOG1EM6);
        mlog[((size_t)(b * H_ + h)) * E_ + e] = ml;
    }
    union { _Float16 f; unsigned short s; } ab;
    ab.f = (_Float16)d;                       // same conversion as prep
    atomicMax(&packT[((size_t)b * N_ + ev) * N_ + eu],
              (((int)ab.s) << 16) | (e + 1));
}

// ---------------------------------------------------------------------------
// helpers
// ---------------------------------------------------------------------------
__device__ __forceinline__ unsigned pkf16(float x, float y)
{
    fp16x2 v = __builtin_amdgcn_cvt_pkrtz(x, y);
    union { fp16x2 h; unsigned u; } c; c.h = v; return c.u;
}

__device__ __forceinline__ half8 pack_pfrag(const float* p)
{
    union { unsigned u[4]; half8 h; } r;
    r.u[0] = pkf16(p[0], p[1]);
    r.u[1] = pkf16(p[2], p[3]);
    r.u[2] = pkf16(p[4], p[5]);
    r.u[3] = pkf16(p[6], p[7]);
    return r.h;
}

__device__ __forceinline__ float av_from_pack(int pk)
{
    union { unsigned short s; _Float16 f; } cc;
    cc.s = (unsigned short)(((unsigned)pk) >> 16);
    return (float)cc.f;
}

// ---------------------------------------------------------------------------
// Kernel 3: MFMA attention, LDS-free — r13-PROVEN STRUCTURE (inline gathers,
// no explicit pipeline; r14's branch+rotation pipeline regressed attn
// 2x because the compiler sank the prefetches at VGPR=88). One wave per
// (b,h,ut) tile; swapped QK^T -> S^T col=lane&31=u; defer-max THR=8.
// ---------------------------------------------------------------------------
__global__ __launch_bounds__(64) void attn_kernel(
    const _Float16* __restrict__ Qf, const _Float16* __restrict__ Kf,
    const _Float16* __restrict__ Vf, const int* __restrict__ packT,
    const float* __restrict__ mlog,
    const float* __restrict__ shifts, const float* __restrict__ widths,
    const float* __restrict__ slw_arr, float* __restrict__ out)
{
    const int bid  = blockIdx.x;          // b*128 + h*16 + ut
    const int b    = bid >> 7;
    const int h    = (bid >> 4) & 7;
    const int ut   = bid & 15;
    const int lane = threadIdx.x;
    const int hi   = lane >> 5;
    const int u0w  = ut * 32;

    const size_t panel = ((size_t)(b * H_ + h) * 16) * 2048; // bytes
    const char* Kp = (const char*)Kf + panel;
    const char* Vp = (const char*)Vf + panel;
    const char* Qp = (const char*)Qf + panel;

    half8 qf0 = *(const half8*)(Qp + (ut * 2 + 0) * 1024 + lane * 16);
    half8 qf1 = *(const half8*)(Qp + (ut * 2 + 1) * 1024 + lane * 16);

    const float s_h   = shifts[h];
    const float w_h   = widths[h];
    const float inv2w = 1.0f / (2.0f * w_h * w_h + 1e-6f);
    const float slw   = slw_arr[h];
    const float* mlg  = mlog + (size_t)(b * H_ + h) * E_;
    const int ucol    = u0w + (lane & 31);
    const int* prow   = packT + (size_t)b * N_ * N_ + ucol;

    f32x16 Oacc;
#pragma unroll
    for (int r = 0; r < 16; r++) Oacc[r] = 0.0f;
    float m = -1e30f, ssum = 0.0f;

    for (int vt = 0; vt < 16; vt++) {
        // QK^T tile (S^T)
        half8 ka0 = *(const half8*)(Kp + (vt * 2 + 0) * 1024 + lane * 16);
        half8 ka1 = *(const half8*)(Kp + (vt * 2 + 1) * 1024 + lane * 16);
        f32x16 C;
#pragma unroll
        for (int r = 0; r < 16; r++) C[r] = 0.0f;
        C = __builtin_amdgcn_mfma_f32_32x32x16_f16(ka0, qf0, C, 0, 0, 0);
        C = __builtin_amdgcn_mfma_f32_32x32x16_f16(ka1, qf1, C, 0, 0, 0);

        // adjust + tile max (pack word inline; compiler batches the 16 loads)
        float p[16];
        float pmax = -1e30f;
        const int vbase = vt * 32 + 4 * hi;
#pragma unroll
        for (int r = 0; r < 16; r++) {
            int vg  = vbase + (r & 3) + 8 * (r >> 2);
            int pkr = prow[(size_t)vg * N_];
            int sv  = (pkr & 0xffff) - 1;
            float av = av_from_pack(pkr);
            float ml = mlg[sv < 0 ? 0 : sv];
            float t  = av - s_h;
            float bl = fmaxf(-(t * t) * inv2w, LOG1EM6);
            float sc = C[r] + (sv >= 0 ? ml : bl);
            if (vg == ucol) sc += slw;
            p[r] = sc;
            pmax = fmaxf(pmax, sc);
        }
        pmax = fmaxf(pmax, __shfl_xor(pmax, 32, 64));

        // defer-max online update (T13, THR=8)
        if (!__all(pmax - m <= 8.0f)) {
            float mnew = fmaxf(m, pmax);
            float scl  = __expf(m - mnew);
#pragma unroll
            for (int r = 0; r < 16; r++) {
                int ur = (r & 3) + 8 * (r >> 2) + 4 * hi;
                Oacc[r] *= __shfl(scl, ur, 64);
            }
            ssum *= scl;
            m = mnew;
        }

#pragma unroll
        for (int r = 0; r < 16; r++) {
            p[r] = __expf(p[r] - m);
            ssum += p[r];
        }

        // pack P (lane-local) + PV MFMA
        half8 pa0 = pack_pfrag(&p[0]);
        half8 pa1 = pack_pfrag(&p[8]);
        half8 vb0 = *(const half8*)(Vp + (vt * 2 + 0) * 1024 + lane * 16);
        half8 vb1 = *(const half8*)(Vp + (vt * 2 + 1) * 1024 + lane * 16);
        Oacc = __builtin_amdgcn_mfma_f32_32x32x16_f16(pa0, vb0, Oacc, 0, 0, 0);
        Oacc = __builtin_amdgcn_mfma_f32_32x32x16_f16(pa1, vb1, Oacc, 0, 0, 0);
    }

    float stot = ssum + __shfl_xor(ssum, 32, 64);
    float rs = 1.0f / stot;
#pragma unroll
    for (int r = 0; r < 16; r++) {
        int ur = (r & 3) + 8 * (r >> 2) + 4 * hi;
        float o = Oacc[r] * __shfl(rs, ur, 64);
        int ug = u0w + ur;
        out[((size_t)(b * N_ + ug)) * D_ + h * HD_ + (lane & 31)] = o;
    }
}

// ---------------------------------------------------------------------------
extern "C" void kernel_launch(void* const* d_in, const int* in_sizes, int n_in,
                              void* d_out, int out_size, void* d_ws, size_t ws_size,
                              hipStream_t stream)
{
    const float* x          = (const float*)d_in[0];
    const float* adj        = (const float*)d_in[1];
    const int*   edge_index = (const int*)d_in[2];
    const float* edge_attr  = (const float*)d_in[3];
    const float* qkv_W      = (const float*)d_in[6];
    const float* qkv_b      = (const float*)d_in[7];
    const float* ds_W       = (const float*)d_in[12];
    const float* ds_b       = (const float*)d_in[13];
    const float* dw_W       = (const float*)d_in[14];
    const float* dw_b       = (const float*)d_in[15];
    const float* shifts     = (const float*)d_in[16];
    const float* widths     = (const float*)d_in[17];
    const float* slw        = (const float*)d_in[18];
    float* out = (float*)d_out;

    // workspace layout (~16.4MB)
    _Float16* Qf   = (_Float16*)d_ws;                      // 2MB
    _Float16* Kf   = Qf + (size_t)B_ * H_ * N_ * HD_;      // 2MB
    _Float16* Vf   = Kf + (size_t)B_ * H_ * N_ * HD_;      // 2MB
    float*    mlog = (float*)(Vf + (size_t)B_ * H_ * N_ * HD_);    // 2MB
    int*      packT = (int*)(mlog + (size_t)B_ * H_ * E_); // 8MB
    _Float16* Wt   = (_Float16*)(packT + (size_t)B_ * N_ * N_);    // 384KB

    prep_kernel<<<dim3(560), 256, 0, stream>>>(packT, qkv_W, Wt, adj);

    hipFuncSetAttribute((const void*)mid_kernel,
                        hipFuncAttributeMaxDynamicSharedMemorySize, 65536);
    mid_kernel<<<dim3(1024), 256, 65536, stream>>>(
        x, Wt, qkv_b, Qf, Kf, Vf,
        edge_attr, edge_index, adj,
        ds_W, ds_b, dw_W, dw_b, shifts, widths, mlog, packT);

    attn_kernel<<<dim3(1024), 64, 0, stream>>>(Qf, Kf, Vf, packT,
                                               mlog, shifts, widths, slw, out);
}

// Round 16
// 50.624 us; speedup vs baseline: 2.0005x; 1.2368x over previous
//
#include <hip/hip_runtime.h>

#define B_ 8
#define N_ 512
#define D_ 256
#define H_ 8
#define HD_ 32
#define E_ 8192
#define EA_ 32

#define LOG1EM6 -13.815510557964274f
#define SCALE 0.17677669529663687f

typedef _Float16 half8 __attribute__((ext_vector_type(8)));
typedef _Float16 half4t __attribute__((ext_vector_type(4)));
typedef __fp16 fp16x2 __attribute__((ext_vector_type(2)));
typedef float f32x16 __attribute__((ext_vector_type(16)));

// ---------------------------------------------------------------------------
// Kernel 1: prep (unchanged, r15-verified).
//  blocks 0..511 : packT[b][v][u] = f16bits(adj[u][v])<<16 | 0
//  blocks 512..559: W (256x768) -> Wt[col][k] f16
// ---------------------------------------------------------------------------
__global__ __launch_bounds__(256) void prep_kernel(
    int* __restrict__ packT, const float* __restrict__ W,
    _Float16* __restrict__ Wt, const float* __restrict__ adj)
{
    __shared__ float t[64][65];
    const int blk = blockIdx.x;
    const int r  = threadIdx.x >> 4;      // 0..15
    const int c4 = (threadIdx.x & 15) * 4;

    if (blk < 512) {
        const int b = blk >> 6, vt = (blk >> 3) & 7, ut = blk & 7;
        const int u0 = ut * 64, v0 = vt * 64;
        const float* src = adj + ((size_t)b * N_ + u0) * N_ + v0;
#pragma unroll
        for (int it = 0; it < 4; it++) {
            int rr = r + it * 16;
            float4 v = *(const float4*)&src[rr * N_ + c4];
            t[rr][c4 + 0] = v.x; t[rr][c4 + 1] = v.y;
            t[rr][c4 + 2] = v.z; t[rr][c4 + 3] = v.w;
        }
        __syncthreads();
        int* dst = packT + ((size_t)b * N_ + v0) * N_ + u0;
#pragma unroll
        for (int it = 0; it < 4; it++) {
            int rr = r + it * 16;
            int4 pv;
            union { _Float16 f; unsigned short s; } cc;
            cc.f = (_Float16)t[c4 + 0][rr]; pv.x = ((int)cc.s) << 16;
            cc.f = (_Float16)t[c4 + 1][rr]; pv.y = ((int)cc.s) << 16;
            cc.f = (_Float16)t[c4 + 2][rr]; pv.z = ((int)cc.s) << 16;
            cc.f = (_Float16)t[c4 + 3][rr]; pv.w = ((int)cc.s) << 16;
            *(int4*)&dst[rr * N_ + c4] = pv;
        }
    } else {
        const int ti = blk - 512;         // 0..47
        const int k0 = (ti / 12) * 64;
        const int n0 = (ti % 12) * 64;
        const float* src = W + (size_t)k0 * 768 + n0;
#pragma unroll
        for (int it = 0; it < 4; it++) {
            int rr = r + it * 16;
            float4 v = *(const float4*)&src[rr * 768 + c4];
            t[rr][c4 + 0] = v.x; t[rr][c4 + 1] = v.y;
            t[rr][c4 + 2] = v.z; t[rr][c4 + 3] = v.w;
        }
        __syncthreads();
        _Float16* dst = Wt + (size_t)n0 * 256 + k0;
#pragma unroll
        for (int it = 0; it < 4; it++) {
            int rr = r + it * 16;
            half4t hv;
#pragma unroll
            for (int kk = 0; kk < 4; kk++) hv[kk] = (_Float16)t[c4 + kk][rr];
            *(half4t*)&dst[rr * 256 + c4] = hv;
        }
    }
}

// ---------------------------------------------------------------------------
// Kernel 2: mid (unchanged, r15-verified) = qkv MFMA GEMM (0..767) +
// edge kernel (768..1023); edge scatters atomicMax(packT, adjbits<<16|e+1).
// ---------------------------------------------------------------------------
__global__ __launch_bounds__(256) void mid_kernel(
    const float* __restrict__ x, const _Float16* __restrict__ Wt,
    const float* __restrict__ bias,
    _Float16* __restrict__ Qf, _Float16* __restrict__ Kf,
    _Float16* __restrict__ Vf,
    const float* __restrict__ edge_attr, const int* __restrict__ edge_index,
    const float* __restrict__ adj,
    const float* __restrict__ ds_W, const float* __restrict__ ds_b,
    const float* __restrict__ dw_W, const float* __restrict__ dw_b,
    const float* __restrict__ shifts, const float* __restrict__ widths,
    float* __restrict__ mlog, int* __restrict__ packT)
{
    extern __shared__ char lds[];
    const int tid = threadIdx.x;
    const int blk = blockIdx.x;

    if (blk < 768) {
        const int m0 = (blk / 12) * 64;
        const int n0 = (blk % 12) * 64;

#pragma unroll
        for (int it = 0; it < 16; it++) {
            int g   = tid + it * 256;
            int row = g & 63, k4 = g >> 6;
            float4 v = *(const float4*)&x[(size_t)(m0 + row) * 256 + k4 * 4];
            union { _Float16 h[4]; uint2 u; } c;
            c.h[0] = (_Float16)v.x; c.h[1] = (_Float16)v.y;
            c.h[2] = (_Float16)v.z; c.h[3] = (_Float16)v.w;
            int ks = k4 >> 2, hb = (k4 >> 1) & 1, lhi = k4 & 1;
            int off = (((row >> 5) * 16 + ks) << 10) +
                      ((lhi * 32 + (row & 31)) << 4) + hb * 8;
            *(uint2*)(lds + off) = c.u;
        }
#pragma unroll
        for (int it = 0; it < 16; it++) {
            int g   = tid + it * 256;
            int col = g & 63, k4 = g >> 6;
            uint2 v = *(const uint2*)&Wt[(size_t)(n0 + col) * 256 + k4 * 4];
            int ks = k4 >> 2, hb = (k4 >> 1) & 1, lhi = k4 & 1;
            int off = 32768 + (((col >> 5) * 16 + ks) << 10) +
                      ((lhi * 32 + (col & 31)) << 4) + hb * 8;
            *(uint2*)(lds + off) = v;
        }
        __syncthreads();

        const int wv = tid >> 6, lane = tid & 63, hi = lane >> 5;
        const int rb = wv & 1, cb = wv >> 1;
        const int c_base = n0 + cb * 32;
        const int which  = c_base >> 8;
        const int h      = (c_base >> 5) & 7;
        const int b      = m0 >> 9;
        const int ut     = ((m0 & 511) >> 5) + rb;

        f32x16 acc;
#pragma unroll
        for (int r = 0; r < 16; r++) acc[r] = 0.0f;

        if (which < 2) {
#pragma unroll
            for (int ks = 0; ks < 16; ks++) {
                half8 af = *(const half8*)(lds + 32768 + (((cb * 16 + ks) << 10)) + lane * 16);
                half8 bf = *(const half8*)(lds + (((rb * 16 + ks) << 10)) + lane * 16);
                acc = __builtin_amdgcn_mfma_f32_32x32x16_f16(af, bf, acc, 0, 0, 0);
            }
            _Float16* dst = (which == 0) ? Qf : Kf;
            const float sc = (which == 0) ? SCALE : 1.0f;
            size_t pb = (((size_t)(b * H_ + h) * 16 + ut) * 2) * 1024;
#pragma unroll
            for (int kh = 0; kh < 2; kh++) {
                union { _Float16 h[8]; int4 q; } fr;
#pragma unroll
                for (int j = 0; j < 8; j++) {
                    int r = kh * 8 + j;
                    int hd = (r & 3) + 8 * (r >> 2) + 4 * hi;
                    fr.h[j] = (_Float16)((acc[r] + bias[c_base + hd]) * sc);
                }
                *(int4*)((char*)dst + pb + kh * 1024 + lane * 16) = fr.q;
            }
        } else {
#pragma unroll
            for (int ks = 0; ks < 16; ks++) {
                half8 af = *(const half8*)(lds + (((rb * 16 + ks) << 10)) + lane * 16);
                half8 bf = *(const half8*)(lds + 32768 + (((cb * 16 + ks) << 10)) + lane * 16);
                acc = __builtin_amdgcn_mfma_f32_32x32x16_f16(af, bf, acc, 0, 0, 0);
            }
            const float bcol = bias[c_base + (lane & 31)];
            size_t pb = (((size_t)(b * H_ + h) * 16 + ut) * 2) * 1024;
#pragma unroll
            for (int kh = 0; kh < 2; kh++) {
                union { _Float16 h[8]; int4 q; } fr;
#pragma unroll
                for (int j = 0; j < 8; j++)
                    fr.h[j] = (_Float16)(acc[kh * 8 + j] + bcol);
                *(int4*)((char*)Vf + pb + kh * 1024 + lane * 16) = fr.q;
            }
        }
        return;
    }

    // ---------------- edge kernel ----------------
    float* ea  = (float*)lds;
    float* dsW = ea + 256 * 33;
    float* dwW = dsW + 256;
    const int eb = blk - 768;
    const int b  = eb >> 5;
    const int e0 = (eb & 31) * 256;

    const float* eabase = edge_attr + ((size_t)b * E_ + e0) * EA_;
#pragma unroll
    for (int it = 0; it < 32; it++) {
        int i = tid + it * 256;
        ea[(i >> 5) * 33 + (i & 31)] = eabase[i];
    }
    dsW[tid] = ds_W[tid];
    dwW[tid] = dw_W[tid];
    __syncthreads();

    const int e  = e0 + tid;
    const int eu = edge_index[(size_t)b * 2 * E_ + e];
    const int ev = edge_index[(size_t)b * 2 * E_ + E_ + e];
    const float d = adj[((size_t)b * N_ + eu) * N_ + ev];

    float ds[8], dw[8];
#pragma unroll
    for (int h = 0; h < 8; h++) { ds[h] = ds_b[h]; dw[h] = dw_b[h]; }
#pragma unroll
    for (int k = 0; k < 32; k++) {
        float a = ea[tid * 33 + k];
#pragma unroll
        for (int h = 0; h < 8; h++) {
            ds[h] += a * dsW[k * 8 + h];
            dw[h] += a * dwW[k * 8 + h];
        }
    }
#pragma unroll
    for (int h = 0; h < 8; h++) {
        float ms = shifts[h] + ds[h];
        float mw = widths[h] + dw[h];
        float t  = d - ms;
        float ml = fmaxf(-(t * t) / (2.0f * mw * mw + 1e-6f), LOG1EM6);
        mlog[((size_t)(b * H_ + h)) * E_ + e] = ml;
    }
    union { _Float16 f; unsigned short s; } ab;
    ab.f = (_Float16)d;                       // same conversion as prep
    atomicMax(&packT[((size_t)b * N_ + ev) * N_ + eu],
              (((int)ab.s) << 16) | (e + 1));
}

// ---------------------------------------------------------------------------
// helpers
// ---------------------------------------------------------------------------
__device__ __forceinline__ unsigned pkf16(float x, float y)
{
    fp16x2 v = __builtin_amdgcn_cvt_pkrtz(x, y);
    union { fp16x2 h; unsigned u; } c; c.h = v; return c.u;
}

__device__ __forceinline__ half8 pack_pfrag(const float* p)
{
    union { unsigned u[4]; half8 h; } r;
    r.u[0] = pkf16(p[0], p[1]);
    r.u[1] = pkf16(p[2], p[3]);
    r.u[2] = pkf16(p[4], p[5]);
    r.u[3] = pkf16(p[6], p[7]);
    return r.h;
}

__device__ __forceinline__ float av_from_pack(int pk)
{
    union { unsigned short s; _Float16 f; } cc;
    cc.s = (unsigned short)(((unsigned)pk) >> 16);
    return (float)cc.f;
}

// ---------------------------------------------------------------------------
// Kernel 3: MFMA attention with 4-WAY FLASH V-SPLIT per block.
// Block = 256 threads (4 waves), grid 1024 (b,h,ut). Wave s computes the
// r13/r15-verified loop over v-tiles [s*4, s*4+4) -> partial (Oacc, m, ssum);
// in-block LDS merge (standard flash combine) by wave 0.
// Effects: 4 waves/SIMD latency hiding + serial tile chain 16 -> 4.
// Hot-loop body is byte-identical to the verified structure (r14 lesson:
// don't add live registers to the loop).
// ---------------------------------------------------------------------------
__global__ __launch_bounds__(256) void attn_kernel(
    const _Float16* __restrict__ Qf, const _Float16* __restrict__ Kf,
    const _Float16* __restrict__ Vf, const int* __restrict__ packT,
    const float* __restrict__ mlog,
    const float* __restrict__ shifts, const float* __restrict__ widths,
    const float* __restrict__ slw_arr, float* __restrict__ out)
{
    __shared__ float ldsO[4][16][64];
    __shared__ float ldsM[4][64];
    __shared__ float ldsS[4][64];

    const int bid  = blockIdx.x;          // b*128 + h*16 + ut
    const int b    = bid >> 7;
    const int h    = (bid >> 4) & 7;
    const int ut   = bid & 15;
    const int wv   = threadIdx.x >> 6;    // v-split id 0..3
    const int lane = threadIdx.x & 63;
    const int hi   = lane >> 5;
    const int u0w  = ut * 32;

    const size_t panel = ((size_t)(b * H_ + h) * 16) * 2048; // bytes
    const char* Kp = (const char*)Kf + panel;
    const char* Vp = (const char*)Vf + panel;
    const char* Qp = (const char*)Qf + panel;

    half8 qf0 = *(const half8*)(Qp + (ut * 2 + 0) * 1024 + lane * 16);
    half8 qf1 = *(const half8*)(Qp + (ut * 2 + 1) * 1024 + lane * 16);

    const float s_h   = shifts[h];
    const float w_h   = widths[h];
    const float inv2w = 1.0f / (2.0f * w_h * w_h + 1e-6f);
    const float slw   = slw_arr[h];
    const float* mlg  = mlog + (size_t)(b * H_ + h) * E_;
    const int ucol    = u0w + (lane & 31);
    const int* prow   = packT + (size_t)b * N_ * N_ + ucol;

    f32x16 Oacc;
#pragma unroll
    for (int r = 0; r < 16; r++) Oacc[r] = 0.0f;
    float m = -1e30f, ssum = 0.0f;

    for (int i = 0; i < 4; i++) {
        const int vt = wv * 4 + i;
        // QK^T tile (S^T)
        half8 ka0 = *(const half8*)(Kp + (vt * 2 + 0) * 1024 + lane * 16);
        half8 ka1 = *(const half8*)(Kp + (vt * 2 + 1) * 1024 + lane * 16);
        f32x16 C;
#pragma unroll
        for (int r = 0; r < 16; r++) C[r] = 0.0f;
        C = __builtin_amdgcn_mfma_f32_32x32x16_f16(ka0, qf0, C, 0, 0, 0);
        C = __builtin_amdgcn_mfma_f32_32x32x16_f16(ka1, qf1, C, 0, 0, 0);

        // adjust + tile max
        float p[16];
        float pmax = -1e30f;
        const int vbase = vt * 32 + 4 * hi;
#pragma unroll
        for (int r = 0; r < 16; r++) {
            int vg  = vbase + (r & 3) + 8 * (r >> 2);
            int pkr = prow[(size_t)vg * N_];
            int sv  = (pkr & 0xffff) - 1;
            float av = av_from_pack(pkr);
            float ml = mlg[sv < 0 ? 0 : sv];
            float t  = av - s_h;
            float bl = fmaxf(-(t * t) * inv2w, LOG1EM6);
            float sc = C[r] + (sv >= 0 ? ml : bl);
            if (vg == ucol) sc += slw;
            p[r] = sc;
            pmax = fmaxf(pmax, sc);
        }
        pmax = fmaxf(pmax, __shfl_xor(pmax, 32, 64));

        // defer-max online update (T13, THR=8)
        if (!__all(pmax - m <= 8.0f)) {
            float mnew = fmaxf(m, pmax);
            float scl  = __expf(m - mnew);
#pragma unroll
            for (int r = 0; r < 16; r++) {
                int ur = (r & 3) + 8 * (r >> 2) + 4 * hi;
                Oacc[r] *= __shfl(scl, ur, 64);
            }
            ssum *= scl;
            m = mnew;
        }

#pragma unroll
        for (int r = 0; r < 16; r++) {
            p[r] = __expf(p[r] - m);
            ssum += p[r];
        }

        // pack P (lane-local) + PV MFMA
        half8 pa0 = pack_pfrag(&p[0]);
        half8 pa1 = pack_pfrag(&p[8]);
        half8 vb0 = *(const half8*)(Vp + (vt * 2 + 0) * 1024 + lane * 16);
        half8 vb1 = *(const half8*)(Vp + (vt * 2 + 1) * 1024 + lane * 16);
        Oacc = __builtin_amdgcn_mfma_f32_32x32x16_f16(pa0, vb0, Oacc, 0, 0, 0);
        Oacc = __builtin_amdgcn_mfma_f32_32x32x16_f16(pa1, vb1, Oacc, 0, 0, 0);
    }

    // publish partials: [s][r][lane] layout = conflict-free b32 per r
#pragma unroll
    for (int r = 0; r < 16; r++) ldsO[wv][r][lane] = Oacc[r];
    ldsM[wv][lane] = m;
    ldsS[wv][lane] = ssum;
    __syncthreads();

    if (wv == 0) {
        // flash merge across 4 splits (per-lane u = lane&31)
        float m0 = ldsM[0][lane], m1 = ldsM[1][lane];
        float m2 = ldsM[2][lane], m3 = ldsM[3][lane];
        float mt = fmaxf(fmaxf(m0, m1), fmaxf(m2, m3));
        float sc0 = __expf(m0 - mt), sc1 = __expf(m1 - mt);
        float sc2 = __expf(m2 - mt), sc3 = __expf(m3 - mt);
        float denom = ldsS[0][lane] * sc0 + ldsS[1][lane] * sc1 +
                      ldsS[2][lane] * sc2 + ldsS[3][lane] * sc3;
        float stot = denom + __shfl_xor(denom, 32, 64);
        float rs = 1.0f / stot;
#pragma unroll
        for (int r = 0; r < 16; r++) {
            int ur = (r & 3) + 8 * (r >> 2) + 4 * hi;
            float o = ldsO[0][r][lane] * __shfl(sc0, ur, 64)
                    + ldsO[1][r][lane] * __shfl(sc1, ur, 64)
                    + ldsO[2][r][lane] * __shfl(sc2, ur, 64)
                    + ldsO[3][r][lane] * __shfl(sc3, ur, 64);
            o *= __shfl(rs, ur, 64);
            int ug = u0w + ur;
            out[((size_t)(b * N_ + ug)) * D_ + h * HD_ + (lane & 31)] = o;
        }
    }
}

// ---------------------------------------------------------------------------
extern "C" void kernel_launch(void* const* d_in, const int* in_sizes, int n_in,
                              void* d_out, int out_size, void* d_ws, size_t ws_size,
                              hipStream_t stream)
{
    const float* x          = (const float*)d_in[0];
    const float* adj        = (const float*)d_in[1];
    const int*   edge_index = (const int*)d_in[2];
    const float* edge_attr  = (const float*)d_in[3];
    const float* qkv_W      = (const float*)d_in[6];
    const float* qkv_b      = (const float*)d_in[7];
    const float* ds_W       = (const float*)d_in[12];
    const float* ds_b       = (const float*)d_in[13];
    const float* dw_W       = (const float*)d_in[14];
    const float* dw_b       = (const float*)d_in[15];
    const float* shifts     = (const float*)d_in[16];
    const float* widths     = (const float*)d_in[17];
    const float* slw        = (const float*)d_in[18];
    float* out = (float*)d_out;

    // workspace layout (~16.4MB)
    _Float16* Qf   = (_Float16*)d_ws;                      // 2MB
    _Float16* Kf   = Qf + (size_t)B_ * H_ * N_ * HD_;      // 2MB
    _Float16* Vf   = Kf + (size_t)B_ * H_ * N_ * HD_;      // 2MB
    float*    mlog = (float*)(Vf + (size_t)B_ * H_ * N_ * HD_);    // 2MB
    int*      packT = (int*)(mlog + (size_t)B_ * H_ * E_); // 8MB
    _Float16* Wt   = (_Float16*)(packT + (size_t)B_ * N_ * N_);    // 384KB

    prep_kernel<<<dim3(560), 256, 0, stream>>>(packT, qkv_W, Wt, adj);

    hipFuncSetAttribute((const void*)mid_kernel,
                        hipFuncAttributeMaxDynamicSharedMemorySize, 65536);
    mid_kernel<<<dim3(1024), 256, 65536, stream>>>(
        x, Wt, qkv_b, Qf, Kf, Vf,
        edge_attr, edge_index, adj,
        ds_W, ds_b, dw_W, dw_b, shifts, widths, mlog, packT);

    attn_kernel<<<dim3(1024), 256, 0, stream>>>(Qf, Kf, Vf, packT,
                                                mlog, shifts, widths, slw, out);
}

// Round 17
// 44.837 us; speedup vs baseline: 2.2588x; 1.1291x over previous
//
#include <hip/hip_runtime.h>

#define B_ 8
#define N_ 512
#define D_ 256
#define H_ 8
#define HD_ 32
#define E_ 8192
#define EA_ 32

#define LOG1EM6 -13.815510557964274f
#define SCALE 0.17677669529663687f

typedef _Float16 half8 __attribute__((ext_vector_type(8)));
typedef _Float16 half4t __attribute__((ext_vector_type(4)));
typedef __fp16 fp16x2 __attribute__((ext_vector_type(2)));
typedef float f32x16 __attribute__((ext_vector_type(16)));

// ---------------------------------------------------------------------------
// Kernel 1: prep (unchanged, r15/r16-verified).
//  blocks 0..511 : packT[b][v][u] = f16bits(adj[u][v])<<16 | 0
//  blocks 512..559: W (256x768) -> Wt[col][k] f16
// ---------------------------------------------------------------------------
__global__ __launch_bounds__(256) void prep_kernel(
    int* __restrict__ packT, const float* __restrict__ W,
    _Float16* __restrict__ Wt, const float* __restrict__ adj)
{
    __shared__ float t[64][65];
    const int blk = blockIdx.x;
    const int r  = threadIdx.x >> 4;      // 0..15
    const int c4 = (threadIdx.x & 15) * 4;

    if (blk < 512) {
        const int b = blk >> 6, vt = (blk >> 3) & 7, ut = blk & 7;
        const int u0 = ut * 64, v0 = vt * 64;
        const float* src = adj + ((size_t)b * N_ + u0) * N_ + v0;
#pragma unroll
        for (int it = 0; it < 4; it++) {
            int rr = r + it * 16;
            float4 v = *(const float4*)&src[rr * N_ + c4];
            t[rr][c4 + 0] = v.x; t[rr][c4 + 1] = v.y;
            t[rr][c4 + 2] = v.z; t[rr][c4 + 3] = v.w;
        }
        __syncthreads();
        int* dst = packT + ((size_t)b * N_ + v0) * N_ + u0;
#pragma unroll
        for (int it = 0; it < 4; it++) {
            int rr = r + it * 16;
            int4 pv;
            union { _Float16 f; unsigned short s; } cc;
            cc.f = (_Float16)t[c4 + 0][rr]; pv.x = ((int)cc.s) << 16;
            cc.f = (_Float16)t[c4 + 1][rr]; pv.y = ((int)cc.s) << 16;
            cc.f = (_Float16)t[c4 + 2][rr]; pv.z = ((int)cc.s) << 16;
            cc.f = (_Float16)t[c4 + 3][rr]; pv.w = ((int)cc.s) << 16;
            *(int4*)&dst[rr * N_ + c4] = pv;
        }
    } else {
        const int ti = blk - 512;         // 0..47
        const int k0 = (ti / 12) * 64;
        const int n0 = (ti % 12) * 64;
        const float* src = W + (size_t)k0 * 768 + n0;
#pragma unroll
        for (int it = 0; it < 4; it++) {
            int rr = r + it * 16;
            float4 v = *(const float4*)&src[rr * 768 + c4];
            t[rr][c4 + 0] = v.x; t[rr][c4 + 1] = v.y;
            t[rr][c4 + 2] = v.z; t[rr][c4 + 3] = v.w;
        }
        __syncthreads();
        _Float16* dst = Wt + (size_t)n0 * 256 + k0;
#pragma unroll
        for (int it = 0; it < 4; it++) {
            int rr = r + it * 16;
            half4t hv;
#pragma unroll
            for (int kk = 0; kk < 4; kk++) hv[kk] = (_Float16)t[c4 + kk][rr];
            *(half4t*)&dst[rr * 256 + c4] = hv;
        }
    }
}

// ---------------------------------------------------------------------------
// Kernel 2: mid = qkv MFMA GEMM (0..767) + edge kernel (768..1023).
// r17 change: COALESCED staging granule map — row=(tid>>2)&63,
// k4=(tid&3)+4*it, so lanes 0-3 read consecutive 16B of one row
// (16 cache lines/wave-instr instead of 64). (row,k4)->LDS offset map
// unchanged => fragment layout identical to the verified one.
// ---------------------------------------------------------------------------
__global__ __launch_bounds__(256) void mid_kernel(
    const float* __restrict__ x, const _Float16* __restrict__ Wt,
    const float* __restrict__ bias,
    _Float16* __restrict__ Qf, _Float16* __restrict__ Kf,
    _Float16* __restrict__ Vf,
    const float* __restrict__ edge_attr, const int* __restrict__ edge_index,
    const float* __restrict__ adj,
    const float* __restrict__ ds_W, const float* __restrict__ ds_b,
    const float* __restrict__ dw_W, const float* __restrict__ dw_b,
    const float* __restrict__ shifts, const float* __restrict__ widths,
    float* __restrict__ mlog, int* __restrict__ packT)
{
    extern __shared__ char lds[];
    const int tid = threadIdx.x;
    const int blk = blockIdx.x;

    if (blk < 768) {
        const int m0 = (blk / 12) * 64;
        const int n0 = (blk % 12) * 64;

        const int srow = (tid >> 2) & 63;     // shared by both stagings
        const int kj   = tid & 3;
        const int shb  = (tid >> 1) & 1;
        const int slhi = tid & 1;

#pragma unroll
        for (int it = 0; it < 16; it++) {
            int k4 = kj + 4 * it;             // ks = it
            float4 v = *(const float4*)&x[(size_t)(m0 + srow) * 256 + k4 * 4];
            union { _Float16 h[4]; uint2 u; } c;
            c.h[0] = (_Float16)v.x; c.h[1] = (_Float16)v.y;
            c.h[2] = (_Float16)v.z; c.h[3] = (_Float16)v.w;
            int off = (((srow >> 5) * 16 + it) << 10) +
                      ((slhi * 32 + (srow & 31)) << 4) + shb * 8;
            *(uint2*)(lds + off) = c.u;
        }
#pragma unroll
        for (int it = 0; it < 16; it++) {
            int k4 = kj + 4 * it;
            uint2 v = *(const uint2*)&Wt[(size_t)(n0 + srow) * 256 + k4 * 4];
            int off = 32768 + (((srow >> 5) * 16 + it) << 10) +
                      ((slhi * 32 + (srow & 31)) << 4) + shb * 8;
            *(uint2*)(lds + off) = v;
        }
        __syncthreads();

        const int wv = tid >> 6, lane = tid & 63, hi = lane >> 5;
        const int rb = wv & 1, cb = wv >> 1;
        const int c_base = n0 + cb * 32;
        const int which  = c_base >> 8;
        const int h      = (c_base >> 5) & 7;
        const int b      = m0 >> 9;
        const int ut     = ((m0 & 511) >> 5) + rb;

        f32x16 acc;
#pragma unroll
        for (int r = 0; r < 16; r++) acc[r] = 0.0f;

        if (which < 2) {
#pragma unroll
            for (int ks = 0; ks < 16; ks++) {
                half8 af = *(const half8*)(lds + 32768 + (((cb * 16 + ks) << 10)) + lane * 16);
                half8 bf = *(const half8*)(lds + (((rb * 16 + ks) << 10)) + lane * 16);
                acc = __builtin_amdgcn_mfma_f32_32x32x16_f16(af, bf, acc, 0, 0, 0);
            }
            _Float16* dst = (which == 0) ? Qf : Kf;
            const float sc = (which == 0) ? SCALE : 1.0f;
            size_t pb = (((size_t)(b * H_ + h) * 16 + ut) * 2) * 1024;
#pragma unroll
            for (int kh = 0; kh < 2; kh++) {
                union { _Float16 h[8]; int4 q; } fr;
#pragma unroll
                for (int j = 0; j < 8; j++) {
                    int r = kh * 8 + j;
                    int hd = (r & 3) + 8 * (r >> 2) + 4 * hi;
                    fr.h[j] = (_Float16)((acc[r] + bias[c_base + hd]) * sc);
                }
                *(int4*)((char*)dst + pb + kh * 1024 + lane * 16) = fr.q;
            }
        } else {
#pragma unroll
            for (int ks = 0; ks < 16; ks++) {
                half8 af = *(const half8*)(lds + (((rb * 16 + ks) << 10)) + lane * 16);
                half8 bf = *(const half8*)(lds + 32768 + (((cb * 16 + ks) << 10)) + lane * 16);
                acc = __builtin_amdgcn_mfma_f32_32x32x16_f16(af, bf, acc, 0, 0, 0);
            }
            const float bcol = bias[c_base + (lane & 31)];
            size_t pb = (((size_t)(b * H_ + h) * 16 + ut) * 2) * 1024;
#pragma unroll
            for (int kh = 0; kh < 2; kh++) {
                union { _Float16 h[8]; int4 q; } fr;
#pragma unroll
                for (int j = 0; j < 8; j++)
                    fr.h[j] = (_Float16)(acc[kh * 8 + j] + bcol);
                *(int4*)((char*)Vf + pb + kh * 1024 + lane * 16) = fr.q;
            }
        }
        return;
    }

    // ---------------- edge kernel (unchanged) ----------------
    float* ea  = (float*)lds;
    float* dsW = ea + 256 * 33;
    float* dwW = dsW + 256;
    const int eb = blk - 768;
    const int b  = eb >> 5;
    const int e0 = (eb & 31) * 256;

    const float* eabase = edge_attr + ((size_t)b * E_ + e0) * EA_;
#pragma unroll
    for (int it = 0; it < 32; it++) {
        int i = tid + it * 256;
        ea[(i >> 5) * 33 + (i & 31)] = eabase[i];
    }
    dsW[tid] = ds_W[tid];
    dwW[tid] = dw_W[tid];
    __syncthreads();

    const int e  = e0 + tid;
    const int eu = edge_index[(size_t)b * 2 * E_ + e];
    const int ev = edge_index[(size_t)b * 2 * E_ + E_ + e];
    const float d = adj[((size_t)b * N_ + eu) * N_ + ev];

    float ds[8], dw[8];
#pragma unroll
    for (int h = 0; h < 8; h++) { ds[h] = ds_b[h]; dw[h] = dw_b[h]; }
#pragma unroll
    for (int k = 0; k < 32; k++) {
        float a = ea[tid * 33 + k];
#pragma unroll
        for (int h = 0; h < 8; h++) {
            ds[h] += a * dsW[k * 8 + h];
            dw[h] += a * dwW[k * 8 + h];
        }
    }
#pragma unroll
    for (int h = 0; h < 8; h++) {
        float ms = shifts[h] + ds[h];
        float mw = widths[h] + dw[h];
        float t  = d - ms;
        float ml = fmaxf(-(t * t) / (2.0f * mw * mw + 1e-6f), LOG1EM6);
        mlog[((size_t)(b * H_ + h)) * E_ + e] = ml;
    }
    union { _Float16 f; unsigned short s; } ab;
    ab.f = (_Float16)d;                       // same conversion as prep
    atomicMax(&packT[((size_t)b * N_ + ev) * N_ + eu],
              (((int)ab.s) << 16) | (e + 1));
}

// ---------------------------------------------------------------------------
// helpers
// ---------------------------------------------------------------------------
__device__ __forceinline__ unsigned pkf16(float x, float y)
{
    fp16x2 v = __builtin_amdgcn_cvt_pkrtz(x, y);
    union { fp16x2 h; unsigned u; } c; c.h = v; return c.u;
}

__device__ __forceinline__ half8 pack_pfrag(const float* p)
{
    union { unsigned u[4]; half8 h; } r;
    r.u[0] = pkf16(p[0], p[1]);
    r.u[1] = pkf16(p[2], p[3]);
    r.u[2] = pkf16(p[4], p[5]);
    r.u[3] = pkf16(p[6], p[7]);
    return r.h;
}

__device__ __forceinline__ float av_from_pack(int pk)
{
    union { unsigned short s; _Float16 f; } cc;
    cc.s = (unsigned short)(((unsigned)pk) >> 16);
    return (float)cc.f;
}

// ---------------------------------------------------------------------------
// Kernel 3: MFMA attention with 8-WAY FLASH V-SPLIT per block.
// Block = 512 threads (8 waves), grid 1024 (b,h,ut). Wave s runs the
// verified loop over v-tiles {2s, 2s+1} -> partial (Oacc, m, ssum).
// 4 blocks/CU = 2048 thr = 8 waves/SIMD (max occupancy; body ~90 VGPR fits
// the 128 cap 512-thread blocks impose). Merge parallelized: wave w writes
// r in {2w, 2w+1} (denom computed redundantly per wave).
// ---------------------------------------------------------------------------
__global__ __launch_bounds__(512) void attn_kernel(
    const _Float16* __restrict__ Qf, const _Float16* __restrict__ Kf,
    const _Float16* __restrict__ Vf, const int* __restrict__ packT,
    const float* __restrict__ mlog,
    const float* __restrict__ shifts, const float* __restrict__ widths,
    const float* __restrict__ slw_arr, float* __restrict__ out)
{
    __shared__ float ldsO[8][16][64];
    __shared__ float ldsM[8][64];
    __shared__ float ldsS[8][64];

    const int bid  = blockIdx.x;          // b*128 + h*16 + ut
    const int b    = bid >> 7;
    const int h    = (bid >> 4) & 7;
    const int ut   = bid & 15;
    const int wv   = threadIdx.x >> 6;    // v-split id 0..7
    const int lane = threadIdx.x & 63;
    const int hi   = lane >> 5;
    const int u0w  = ut * 32;

    const size_t panel = ((size_t)(b * H_ + h) * 16) * 2048; // bytes
    const char* Kp = (const char*)Kf + panel;
    const char* Vp = (const char*)Vf + panel;
    const char* Qp = (const char*)Qf + panel;

    half8 qf0 = *(const half8*)(Qp + (ut * 2 + 0) * 1024 + lane * 16);
    half8 qf1 = *(const half8*)(Qp + (ut * 2 + 1) * 1024 + lane * 16);

    const float s_h   = shifts[h];
    const float w_h   = widths[h];
    const float inv2w = 1.0f / (2.0f * w_h * w_h + 1e-6f);
    const float slw   = slw_arr[h];
    const float* mlg  = mlog + (size_t)(b * H_ + h) * E_;
    const int ucol    = u0w + (lane & 31);
    const int* prow   = packT + (size_t)b * N_ * N_ + ucol;

    f32x16 Oacc;
#pragma unroll
    for (int r = 0; r < 16; r++) Oacc[r] = 0.0f;
    float m = -1e30f, ssum = 0.0f;

#pragma unroll
    for (int i = 0; i < 2; i++) {
        const int vt = wv * 2 + i;
        // QK^T tile (S^T)
        half8 ka0 = *(const half8*)(Kp + (vt * 2 + 0) * 1024 + lane * 16);
        half8 ka1 = *(const half8*)(Kp + (vt * 2 + 1) * 1024 + lane * 16);
        f32x16 C;
#pragma unroll
        for (int r = 0; r < 16; r++) C[r] = 0.0f;
        C = __builtin_amdgcn_mfma_f32_32x32x16_f16(ka0, qf0, C, 0, 0, 0);
        C = __builtin_amdgcn_mfma_f32_32x32x16_f16(ka1, qf1, C, 0, 0, 0);

        // adjust + tile max
        float p[16];
        float pmax = -1e30f;
        const int vbase = vt * 32 + 4 * hi;
#pragma unroll
        for (int r = 0; r < 16; r++) {
            int vg  = vbase + (r & 3) + 8 * (r >> 2);
            int pkr = prow[(size_t)vg * N_];
            int sv  = (pkr & 0xffff) - 1;
            float av = av_from_pack(pkr);
            float ml = mlg[sv < 0 ? 0 : sv];
            float t  = av - s_h;
            float bl = fmaxf(-(t * t) * inv2w, LOG1EM6);
            float sc = C[r] + (sv >= 0 ? ml : bl);
            if (vg == ucol) sc += slw;
            p[r] = sc;
            pmax = fmaxf(pmax, sc);
        }
        pmax = fmaxf(pmax, __shfl_xor(pmax, 32, 64));

        // defer-max online update (T13, THR=8)
        if (!__all(pmax - m <= 8.0f)) {
            float mnew = fmaxf(m, pmax);
            float scl  = __expf(m - mnew);
#pragma unroll
            for (int r = 0; r < 16; r++) {
                int ur = (r & 3) + 8 * (r >> 2) + 4 * hi;
                Oacc[r] *= __shfl(scl, ur, 64);
            }
            ssum *= scl;
            m = mnew;
        }

#pragma unroll
        for (int r = 0; r < 16; r++) {
            p[r] = __expf(p[r] - m);
            ssum += p[r];
        }

        // pack P (lane-local) + PV MFMA
        half8 pa0 = pack_pfrag(&p[0]);
        half8 pa1 = pack_pfrag(&p[8]);
        half8 vb0 = *(const half8*)(Vp + (vt * 2 + 0) * 1024 + lane * 16);
        half8 vb1 = *(const half8*)(Vp + (vt * 2 + 1) * 1024 + lane * 16);
        Oacc = __builtin_amdgcn_mfma_f32_32x32x16_f16(pa0, vb0, Oacc, 0, 0, 0);
        Oacc = __builtin_amdgcn_mfma_f32_32x32x16_f16(pa1, vb1, Oacc, 0, 0, 0);
    }

    // publish partials
#pragma unroll
    for (int r = 0; r < 16; r++) ldsO[wv][r][lane] = Oacc[r];
    ldsM[wv][lane] = m;
    ldsS[wv][lane] = ssum;
    __syncthreads();

    // flash merge: every wave computes scales (redundant), writes 2 r-values
    float ms_[8], ss_[8];
#pragma unroll
    for (int s = 0; s < 8; s++) { ms_[s] = ldsM[s][lane]; ss_[s] = ldsS[s][lane]; }
    float mt = ms_[0];
#pragma unroll
    for (int s = 1; s < 8; s++) mt = fmaxf(mt, ms_[s]);
    float scs[8];
    float denom = 0.0f;
#pragma unroll
    for (int s = 0; s < 8; s++) {
        scs[s] = __expf(ms_[s] - mt);
        denom += ss_[s] * scs[s];
    }
    float stot = denom + __shfl_xor(denom, 32, 64);
    float rs = 1.0f / stot;

#pragma unroll
    for (int rr = 0; rr < 2; rr++) {
        int r  = wv * 2 + rr;
        int ur = (r & 3) + 8 * (r >> 2) + 4 * hi;
        float o = 0.0f;
#pragma unroll
        for (int s = 0; s < 8; s++)
            o += ldsO[s][r][lane] * __shfl(scs[s], ur, 64);
        o *= __shfl(rs, ur, 64);
        int ug = u0w + ur;
        out[((size_t)(b * N_ + ug)) * D_ + h * HD_ + (lane & 31)] = o;
    }
}

// ---------------------------------------------------------------------------
extern "C" void kernel_launch(void* const* d_in, const int* in_sizes, int n_in,
                              void* d_out, int out_size, void* d_ws, size_t ws_size,
                              hipStream_t stream)
{
    const float* x          = (const float*)d_in[0];
    const float* adj        = (const float*)d_in[1];
    const int*   edge_index = (const int*)d_in[2];
    const float* edge_attr  = (const float*)d_in[3];
    const float* qkv_W      = (const float*)d_in[6];
    const float* qkv_b      = (const float*)d_in[7];
    const float* ds_W       = (const float*)d_in[12];
    const float* ds_b       = (const float*)d_in[13];
    const float* dw_W       = (const float*)d_in[14];
    const float* dw_b       = (const float*)d_in[15];
    const float* shifts     = (const float*)d_in[16];
    const float* widths     = (const float*)d_in[17];
    const float* slw        = (const float*)d_in[18];
    float* out = (float*)d_out;

    // workspace layout (~16.4MB)
    _Float16* Qf   = (_Float16*)d_ws;                      // 2MB
    _Float16* Kf   = Qf + (size_t)B_ * H_ * N_ * HD_;      // 2MB
    _Float16* Vf   = Kf + (size_t)B_ * H_ * N_ * HD_;      // 2MB
    float*    mlog = (float*)(Vf + (size_t)B_ * H_ * N_ * HD_);    // 2MB
    int*      packT = (int*)(mlog + (size_t)B_ * H_ * E_); // 8MB
    _Float16* Wt   = (_Float16*)(packT + (size_t)B_ * N_ * N_);    // 384KB

    prep_kernel<<<dim3(560), 256, 0, stream>>>(packT, qkv_W, Wt, adj);

    hipFuncSetAttribute((const void*)mid_kernel,
                        hipFuncAttributeMaxDynamicSharedMemorySize, 65536);
    mid_kernel<<<dim3(1024), 256, 65536, stream>>>(
        x, Wt, qkv_b, Qf, Kf, Vf,
        edge_attr, edge_index, adj,
        ds_W, ds_b, dw_W, dw_b, shifts, widths, mlog, packT);

    attn_kernel<<<dim3(1024), 512, 0, stream>>>(Qf, Kf, Vf, packT,
                                                mlog, shifts, widths, slw, out);
}

// Round 18
// 43.345 us; speedup vs baseline: 2.3365x; 1.0344x over previous
//
#include <hip/hip_runtime.h>

#define B_ 8
#define N_ 512
#define D_ 256
#define H_ 8
#define HD_ 32
#define E_ 8192
#define EA_ 32

#define LOG1EM6 -13.815510557964274f
#define SCALE 0.17677669529663687f

typedef _Float16 half8 __attribute__((ext_vector_type(8)));
typedef _Float16 half4t __attribute__((ext_vector_type(4)));
typedef __fp16 fp16x2 __attribute__((ext_vector_type(2)));
typedef float f32x16 __attribute__((ext_vector_type(16)));

// ---------------------------------------------------------------------------
// Kernel 1: prep.
//  blocks   0..511: packT[b][v][u] = f16bits(adj[u][v])<<16 | 0
//  blocks 512..559: W (256x768) -> Wfrag (B-fragment layout, 384KB)
//  blocks 560..687: x (4096x256 f32) -> xfrag (A-fragment layout f16, 2MB)
// Fragment offset formula (bytes) — identical to the r17-verified staging:
//   off = ((tile*16 + ks) << 10) + ((lhi*32 + r32) << 4) + hb*8
//   where for k-quad k4: ks=k4>>2, hb=(k4>>1)&1, lhi=k4&1.
// ---------------------------------------------------------------------------
__global__ __launch_bounds__(256) void prep_kernel(
    int* __restrict__ packT, const float* __restrict__ W,
    _Float16* __restrict__ Wfrag, const float* __restrict__ adj,
    const float* __restrict__ x, _Float16* __restrict__ xfrag)
{
    __shared__ float t[64][65];
    const int blk = blockIdx.x;
    const int tid = threadIdx.x;

    if (blk < 512) {
        const int r  = tid >> 4;
        const int c4 = (tid & 15) * 4;
        const int b = blk >> 6, vt = (blk >> 3) & 7, ut = blk & 7;
        const int u0 = ut * 64, v0 = vt * 64;
        const float* src = adj + ((size_t)b * N_ + u0) * N_ + v0;
#pragma unroll
        for (int it = 0; it < 4; it++) {
            int rr = r + it * 16;
            float4 v = *(const float4*)&src[rr * N_ + c4];
            t[rr][c4 + 0] = v.x; t[rr][c4 + 1] = v.y;
            t[rr][c4 + 2] = v.z; t[rr][c4 + 3] = v.w;
        }
        __syncthreads();
        int* dst = packT + ((size_t)b * N_ + v0) * N_ + u0;
#pragma unroll
        for (int it = 0; it < 4; it++) {
            int rr = r + it * 16;
            int4 pv;
            union { _Float16 f; unsigned short s; } cc;
            cc.f = (_Float16)t[c4 + 0][rr]; pv.x = ((int)cc.s) << 16;
            cc.f = (_Float16)t[c4 + 1][rr]; pv.y = ((int)cc.s) << 16;
            cc.f = (_Float16)t[c4 + 2][rr]; pv.z = ((int)cc.s) << 16;
            cc.f = (_Float16)t[c4 + 3][rr]; pv.w = ((int)cc.s) << 16;
            *(int4*)&dst[rr * N_ + c4] = pv;
        }
    } else if (blk < 560) {
        // W tile (64k x 64n) -> B-fragments
        const int r  = tid >> 4;              // k-local row group
        const int c4 = (tid & 15) * 4;        // n-local quad base
        const int ti = blk - 512;             // 0..47
        const int k0 = (ti / 12) * 64;
        const int n0 = (ti % 12) * 64;
        const float* src = W + (size_t)k0 * 768 + n0;
#pragma unroll
        for (int it = 0; it < 4; it++) {
            int rr = r + it * 16;
            float4 v = *(const float4*)&src[rr * 768 + c4];
            t[rr][c4 + 0] = v.x; t[rr][c4 + 1] = v.y;
            t[rr][c4 + 2] = v.z; t[rr][c4 + 3] = v.w;
        }
        __syncthreads();
        // after transpose: thread holds W[k0+c4+kk][n0+rr] for kk=0..3
        const int k4  = (k0 >> 2) + (tid & 15);   // global k-quad
        const int ks  = k4 >> 2;
        const int hb  = (k4 >> 1) & 1;
        const int lhi = k4 & 1;
#pragma unroll
        for (int it = 0; it < 4; it++) {
            int rr  = r + it * 16;                // n-local col
            int col = n0 + rr;
            union { _Float16 h[4]; uint2 u; } c;
#pragma unroll
            for (int kk = 0; kk < 4; kk++) c.h[kk] = (_Float16)t[c4 + kk][rr];
            int off = (((col >> 5) * 16 + ks) << 10) +
                      ((lhi * 32 + (col & 31)) << 4) + hb * 8;
            *(uint2*)((char*)Wfrag + off) = c.u;
        }
    } else {
        // x row-tile (32 rows x 256 k) -> A-fragments (f16)
        const int rt = blk - 560;             // 0..127
        const float* src = x + (size_t)rt * 32 * 256;
        char* dstbase = (char*)xfrag + (size_t)rt * 16384;
#pragma unroll
        for (int it = 0; it < 8; it++) {
            int g   = tid + it * 256;         // 0..2047
            int row = g >> 6;                 // 0..31
            int k4  = g & 63;                 // global k-quad (k0=0)
            float4 v = *(const float4*)&src[row * 256 + k4 * 4];
            union { _Float16 h[4]; uint2 u; } c;
            c.h[0] = (_Float16)v.x; c.h[1] = (_Float16)v.y;
            c.h[2] = (_Float16)v.z; c.h[3] = (_Float16)v.w;
            int ks = k4 >> 2, hb = (k4 >> 1) & 1, lhi = k4 & 1;
            int off = (ks << 10) + ((lhi * 32 + row) << 4) + hb * 8;
            *(uint2*)(dstbase + off) = c.u;
        }
    }
}

// ---------------------------------------------------------------------------
// Kernel 2: mid = qkv MFMA GEMM (0..767, LDS-FREE frag-direct) +
//           edge kernel (768..1023).
// qkv: each wave owns one 32x32 C-tile; af/bf read as linear lane*16 16B
// loads from the L2-hot xfrag/Wfrag panels (identical structure to the
// verified attn loop). No LDS, no barrier, no per-block f32->f16 cvt.
// ---------------------------------------------------------------------------
__global__ __launch_bounds__(256) void mid_kernel(
    const _Float16* __restrict__ xfrag, const _Float16* __restrict__ Wfrag,
    const float* __restrict__ bias,
    _Float16* __restrict__ Qf, _Float16* __restrict__ Kf,
    _Float16* __restrict__ Vf,
    const float* __restrict__ edge_attr, const int* __restrict__ edge_index,
    const float* __restrict__ adj,
    const float* __restrict__ ds_W, const float* __restrict__ ds_b,
    const float* __restrict__ dw_W, const float* __restrict__ dw_b,
    const float* __restrict__ shifts, const float* __restrict__ widths,
    float* __restrict__ mlog, int* __restrict__ packT)
{
    extern __shared__ char lds[];             // used only by the edge path
    const int tid = threadIdx.x;
    const int blk = blockIdx.x;

    if (blk < 768) {
        const int m0 = (blk / 12) * 64;
        const int n0 = (blk % 12) * 64;

        const int wv = tid >> 6, lane = tid & 63, hi = lane >> 5;
        const int rb = wv & 1, cb = wv >> 1;
        const int rbg = (m0 >> 5) + rb;       // global row-tile 0..127
        const int ctg = (n0 >> 5) + cb;       // global col-tile 0..23
        const int c_base = n0 + cb * 32;
        const int which  = c_base >> 8;
        const int h      = (c_base >> 5) & 7;
        const int b      = m0 >> 9;
        const int ut     = ((m0 & 511) >> 5) + rb;

        const char* Ap = (const char*)xfrag + ((size_t)rbg << 14); // *16384
        const char* Bp = (const char*)Wfrag + ((size_t)ctg << 14);

        f32x16 acc;
#pragma unroll
        for (int r = 0; r < 16; r++) acc[r] = 0.0f;

        if (which < 2) {
            // swapped: C^T, lane owns n-row
#pragma unroll
            for (int ks = 0; ks < 16; ks++) {
                half8 af = *(const half8*)(Bp + (ks << 10) + lane * 16);
                half8 bf = *(const half8*)(Ap + (ks << 10) + lane * 16);
                acc = __builtin_amdgcn_mfma_f32_32x32x16_f16(af, bf, acc, 0, 0, 0);
            }
            _Float16* dst = (which == 0) ? Qf : Kf;
            const float sc = (which == 0) ? SCALE : 1.0f;
            size_t pb = (((size_t)(b * H_ + h) * 16 + ut) * 2) * 1024;
#pragma unroll
            for (int kh = 0; kh < 2; kh++) {
                union { _Float16 h[8]; int4 q; } fr;
#pragma unroll
                for (int j = 0; j < 8; j++) {
                    int r = kh * 8 + j;
                    int hd = (r & 3) + 8 * (r >> 2) + 4 * hi;
                    fr.h[j] = (_Float16)((acc[r] + bias[c_base + hd]) * sc);
                }
                *(int4*)((char*)dst + pb + kh * 1024 + lane * 16) = fr.q;
            }
        } else {
            // normal: lane owns hd-col
#pragma unroll
            for (int ks = 0; ks < 16; ks++) {
                half8 af = *(const half8*)(Ap + (ks << 10) + lane * 16);
                half8 bf = *(const half8*)(Bp + (ks << 10) + lane * 16);
                acc = __builtin_amdgcn_mfma_f32_32x32x16_f16(af, bf, acc, 0, 0, 0);
            }
            const float bcol = bias[c_base + (lane & 31)];
            size_t pb = (((size_t)(b * H_ + h) * 16 + ut) * 2) * 1024;
#pragma unroll
            for (int kh = 0; kh < 2; kh++) {
                union { _Float16 h[8]; int4 q; } fr;
#pragma unroll
                for (int j = 0; j < 8; j++)
                    fr.h[j] = (_Float16)(acc[kh * 8 + j] + bcol);
                *(int4*)((char*)Vf + pb + kh * 1024 + lane * 16) = fr.q;
            }
        }
        return;
    }

    // ---------------- edge kernel (unchanged, r15-verified) ----------------
    float* ea  = (float*)lds;
    float* dsW = ea + 256 * 33;
    float* dwW = dsW + 256;
    const int eb = blk - 768;
    const int b  = eb >> 5;
    const int e0 = (eb & 31) * 256;

    const float* eabase = edge_attr + ((size_t)b * E_ + e0) * EA_;
#pragma unroll
    for (int it = 0; it < 32; it++) {
        int i = tid + it * 256;
        ea[(i >> 5) * 33 + (i & 31)] = eabase[i];
    }
    dsW[tid] = ds_W[tid];
    dwW[tid] = dw_W[tid];
    __syncthreads();

    const int e  = e0 + tid;
    const int eu = edge_index[(size_t)b * 2 * E_ + e];
    const int ev = edge_index[(size_t)b * 2 * E_ + E_ + e];
    const float d = adj[((size_t)b * N_ + eu) * N_ + ev];

    float ds[8], dw[8];
#pragma unroll
    for (int h = 0; h < 8; h++) { ds[h] = ds_b[h]; dw[h] = dw_b[h]; }
#pragma unroll
    for (int k = 0; k < 32; k++) {
        float a = ea[tid * 33 + k];
#pragma unroll
        for (int h = 0; h < 8; h++) {
            ds[h] += a * dsW[k * 8 + h];
            dw[h] += a * dwW[k * 8 + h];
        }
    }
#pragma unroll
    for (int h = 0; h < 8; h++) {
        float ms = shifts[h] + ds[h];
        float mw = widths[h] + dw[h];
        float t  = d - ms;
        float ml = fmaxf(-(t * t) / (2.0f * mw * mw + 1e-6f), LOG1EM6);
        mlog[((size_t)(b * H_ + h)) * E_ + e] = ml;
    }
    union { _Float16 f; unsigned short s; } ab;
    ab.f = (_Float16)d;                       // same conversion as prep
    atomicMax(&packT[((size_t)b * N_ + ev) * N_ + eu],
              (((int)ab.s) << 16) | (e + 1));
}

// ---------------------------------------------------------------------------
// helpers
// ---------------------------------------------------------------------------
__device__ __forceinline__ unsigned pkf16(float x, float y)
{
    fp16x2 v = __builtin_amdgcn_cvt_pkrtz(x, y);
    union { fp16x2 h; unsigned u; } c; c.h = v; return c.u;
}

__device__ __forceinline__ half8 pack_pfrag(const float* p)
{
    union { unsigned u[4]; half8 h; } r;
    r.u[0] = pkf16(p[0], p[1]);
    r.u[1] = pkf16(p[2], p[3]);
    r.u[2] = pkf16(p[4], p[5]);
    r.u[3] = pkf16(p[6], p[7]);
    return r.h;
}

__device__ __forceinline__ float av_from_pack(int pk)
{
    union { unsigned short s; _Float16 f; } cc;
    cc.s = (unsigned short)(((unsigned)pk) >> 16);
    return (float)cc.f;
}

// ---------------------------------------------------------------------------
// Kernel 3: MFMA attention, 8-way flash v-split (unchanged, r17-verified).
// ---------------------------------------------------------------------------
__global__ __launch_bounds__(512) void attn_kernel(
    const _Float16* __restrict__ Qf, const _Float16* __restrict__ Kf,
    const _Float16* __restrict__ Vf, const int* __restrict__ packT,
    const float* __restrict__ mlog,
    const float* __restrict__ shifts, const float* __restrict__ widths,
    const float* __restrict__ slw_arr, float* __restrict__ out)
{
    __shared__ float ldsO[8][16][64];
    __shared__ float ldsM[8][64];
    __shared__ float ldsS[8][64];

    const int bid  = blockIdx.x;          // b*128 + h*16 + ut
    const int b    = bid >> 7;
    const int h    = (bid >> 4) & 7;
    const int ut   = bid & 15;
    const int wv   = threadIdx.x >> 6;    // v-split id 0..7
    const int lane = threadIdx.x & 63;
    const int hi   = lane >> 5;
    const int u0w  = ut * 32;

    const size_t panel = ((size_t)(b * H_ + h) * 16) * 2048; // bytes
    const char* Kp = (const char*)Kf + panel;
    const char* Vp = (const char*)Vf + panel;
    const char* Qp = (const char*)Qf + panel;

    half8 qf0 = *(const half8*)(Qp + (ut * 2 + 0) * 1024 + lane * 16);
    half8 qf1 = *(const half8*)(Qp + (ut * 2 + 1) * 1024 + lane * 16);

    const float s_h   = shifts[h];
    const float w_h   = widths[h];
    const float inv2w = 1.0f / (2.0f * w_h * w_h + 1e-6f);
    const float slw   = slw_arr[h];
    const float* mlg  = mlog + (size_t)(b * H_ + h) * E_;
    const int ucol    = u0w + (lane & 31);
    const int* prow   = packT + (size_t)b * N_ * N_ + ucol;

    f32x16 Oacc;
#pragma unroll
    for (int r = 0; r < 16; r++) Oacc[r] = 0.0f;
    float m = -1e30f, ssum = 0.0f;

#pragma unroll
    for (int i = 0; i < 2; i++) {
        const int vt = wv * 2 + i;
        half8 ka0 = *(const half8*)(Kp + (vt * 2 + 0) * 1024 + lane * 16);
        half8 ka1 = *(const half8*)(Kp + (vt * 2 + 1) * 1024 + lane * 16);
        f32x16 C;
#pragma unroll
        for (int r = 0; r < 16; r++) C[r] = 0.0f;
        C = __builtin_amdgcn_mfma_f32_32x32x16_f16(ka0, qf0, C, 0, 0, 0);
        C = __builtin_amdgcn_mfma_f32_32x32x16_f16(ka1, qf1, C, 0, 0, 0);

        float p[16];
        float pmax = -1e30f;
        const int vbase = vt * 32 + 4 * hi;
#pragma unroll
        for (int r = 0; r < 16; r++) {
            int vg  = vbase + (r & 3) + 8 * (r >> 2);
            int pkr = prow[(size_t)vg * N_];
            int sv  = (pkr & 0xffff) - 1;
            float av = av_from_pack(pkr);
            float ml = mlg[sv < 0 ? 0 : sv];
            float t  = av - s_h;
            float bl = fmaxf(-(t * t) * inv2w, LOG1EM6);
            float sc = C[r] + (sv >= 0 ? ml : bl);
            if (vg == ucol) sc += slw;
            p[r] = sc;
            pmax = fmaxf(pmax, sc);
        }
        pmax = fmaxf(pmax, __shfl_xor(pmax, 32, 64));

        if (!__all(pmax - m <= 8.0f)) {
            float mnew = fmaxf(m, pmax);
            float scl  = __expf(m - mnew);
#pragma unroll
            for (int r = 0; r < 16; r++) {
                int ur = (r & 3) + 8 * (r >> 2) + 4 * hi;
                Oacc[r] *= __shfl(scl, ur, 64);
            }
            ssum *= scl;
            m = mnew;
        }

#pragma unroll
        for (int r = 0; r < 16; r++) {
            p[r] = __expf(p[r] - m);
            ssum += p[r];
        }

        half8 pa0 = pack_pfrag(&p[0]);
        half8 pa1 = pack_pfrag(&p[8]);
        half8 vb0 = *(const half8*)(Vp + (vt * 2 + 0) * 1024 + lane * 16);
        half8 vb1 = *(const half8*)(Vp + (vt * 2 + 1) * 1024 + lane * 16);
        Oacc = __builtin_amdgcn_mfma_f32_32x32x16_f16(pa0, vb0, Oacc, 0, 0, 0);
        Oacc = __builtin_amdgcn_mfma_f32_32x32x16_f16(pa1, vb1, Oacc, 0, 0, 0);
    }

#pragma unroll
    for (int r = 0; r < 16; r++) ldsO[wv][r][lane] = Oacc[r];
    ldsM[wv][lane] = m;
    ldsS[wv][lane] = ssum;
    __syncthreads();

    float ms_[8], ss_[8];
#pragma unroll
    for (int s = 0; s < 8; s++) { ms_[s] = ldsM[s][lane]; ss_[s] = ldsS[s][lane]; }
    float mt = ms_[0];
#pragma unroll
    for (int s = 1; s < 8; s++) mt = fmaxf(mt, ms_[s]);
    float scs[8];
    float denom = 0.0f;
#pragma unroll
    for (int s = 0; s < 8; s++) {
        scs[s] = __expf(ms_[s] - mt);
        denom += ss_[s] * scs[s];
    }
    float stot = denom + __shfl_xor(denom, 32, 64);
    float rs = 1.0f / stot;

#pragma unroll
    for (int rr = 0; rr < 2; rr++) {
        int r  = wv * 2 + rr;
        int ur = (r & 3) + 8 * (r >> 2) + 4 * hi;
        float o = 0.0f;
#pragma unroll
        for (int s = 0; s < 8; s++)
            o += ldsO[s][r][lane] * __shfl(scs[s], ur, 64);
        o *= __shfl(rs, ur, 64);
        int ug = u0w + ur;
        out[((size_t)(b * N_ + ug)) * D_ + h * HD_ + (lane & 31)] = o;
    }
}

// ---------------------------------------------------------------------------
extern "C" void kernel_launch(void* const* d_in, const int* in_sizes, int n_in,
                              void* d_out, int out_size, void* d_ws, size_t ws_size,
                              hipStream_t stream)
{
    const float* x          = (const float*)d_in[0];
    const float* adj        = (const float*)d_in[1];
    const int*   edge_index = (const int*)d_in[2];
    const float* edge_attr  = (const float*)d_in[3];
    const float* qkv_W      = (const float*)d_in[6];
    const float* qkv_b      = (const float*)d_in[7];
    const float* ds_W       = (const float*)d_in[12];
    const float* ds_b       = (const float*)d_in[13];
    const float* dw_W       = (const float*)d_in[14];
    const float* dw_b       = (const float*)d_in[15];
    const float* shifts     = (const float*)d_in[16];
    const float* widths     = (const float*)d_in[17];
    const float* slw        = (const float*)d_in[18];
    float* out = (float*)d_out;

    // workspace layout (~18.4MB)
    _Float16* Qf    = (_Float16*)d_ws;                     // 2MB
    _Float16* Kf    = Qf + (size_t)B_ * H_ * N_ * HD_;     // 2MB
    _Float16* Vf    = Kf + (size_t)B_ * H_ * N_ * HD_;     // 2MB
    float*    mlog  = (float*)(Vf + (size_t)B_ * H_ * N_ * HD_);   // 2MB
    int*      packT = (int*)(mlog + (size_t)B_ * H_ * E_); // 8MB
    _Float16* xfrag = (_Float16*)(packT + (size_t)B_ * N_ * N_);   // 2MB
    _Float16* Wfrag = xfrag + (size_t)B_ * N_ * D_;        // 384KB

    prep_kernel<<<dim3(688), 256, 0, stream>>>(packT, qkv_W, Wfrag, adj,
                                               x, xfrag);

    hipFuncSetAttribute((const void*)mid_kernel,
                        hipFuncAttributeMaxDynamicSharedMemorySize, 65536);
    mid_kernel<<<dim3(1024), 256, 65536, stream>>>(
        xfrag, Wfrag, qkv_b, Qf, Kf, Vf,
        edge_attr, edge_index, adj,
        ds_W, ds_b, dw_W, dw_b, shifts, widths, mlog, packT);

    attn_kernel<<<dim3(1024), 512, 0, stream>>>(Qf, Kf, Vf, packT,
                                                mlog, shifts, widths, slw, out);
}

// Round 19
// 42.994 us; speedup vs baseline: 2.3556x; 1.0082x over previous
//
#include <hip/hip_runtime.h>

#define B_ 8
#define N_ 512
#define D_ 256
#define H_ 8
#define HD_ 32
#define E_ 8192
#define EA_ 32

#define LOG1EM6 -13.815510557964274f
#define SCALE 0.17677669529663687f

typedef _Float16 half8 __attribute__((ext_vector_type(8)));
typedef _Float16 half4t __attribute__((ext_vector_type(4)));
typedef __fp16 fp16x2 __attribute__((ext_vector_type(2)));
typedef float f32x16 __attribute__((ext_vector_type(16)));

// ---------------------------------------------------------------------------
// Kernel 1: prep (unchanged, r18-verified).
//  blocks   0..511: packT[b][v][u] = f16bits(adj[u][v])<<16 | 0
//  blocks 512..559: W (256x768) -> Wfrag (B-fragment layout, 384KB)
//  blocks 560..687: x (4096x256 f32) -> xfrag (A-fragment layout f16, 2MB)
// ---------------------------------------------------------------------------
__global__ __launch_bounds__(256) void prep_kernel(
    int* __restrict__ packT, const float* __restrict__ W,
    _Float16* __restrict__ Wfrag, const float* __restrict__ adj,
    const float* __restrict__ x, _Float16* __restrict__ xfrag)
{
    __shared__ float t[64][65];
    const int blk = blockIdx.x;
    const int tid = threadIdx.x;

    if (blk < 512) {
        const int r  = tid >> 4;
        const int c4 = (tid & 15) * 4;
        const int b = blk >> 6, vt = (blk >> 3) & 7, ut = blk & 7;
        const int u0 = ut * 64, v0 = vt * 64;
        const float* src = adj + ((size_t)b * N_ + u0) * N_ + v0;
#pragma unroll
        for (int it = 0; it < 4; it++) {
            int rr = r + it * 16;
            float4 v = *(const float4*)&src[rr * N_ + c4];
            t[rr][c4 + 0] = v.x; t[rr][c4 + 1] = v.y;
            t[rr][c4 + 2] = v.z; t[rr][c4 + 3] = v.w;
        }
        __syncthreads();
        int* dst = packT + ((size_t)b * N_ + v0) * N_ + u0;
#pragma unroll
        for (int it = 0; it < 4; it++) {
            int rr = r + it * 16;
            int4 pv;
            union { _Float16 f; unsigned short s; } cc;
            cc.f = (_Float16)t[c4 + 0][rr]; pv.x = ((int)cc.s) << 16;
            cc.f = (_Float16)t[c4 + 1][rr]; pv.y = ((int)cc.s) << 16;
            cc.f = (_Float16)t[c4 + 2][rr]; pv.z = ((int)cc.s) << 16;
            cc.f = (_Float16)t[c4 + 3][rr]; pv.w = ((int)cc.s) << 16;
            *(int4*)&dst[rr * N_ + c4] = pv;
        }
    } else if (blk < 560) {
        // W tile (64k x 64n) -> B-fragments
        const int r  = tid >> 4;
        const int c4 = (tid & 15) * 4;
        const int ti = blk - 512;             // 0..47
        const int k0 = (ti / 12) * 64;
        const int n0 = (ti % 12) * 64;
        const float* src = W + (size_t)k0 * 768 + n0;
#pragma unroll
        for (int it = 0; it < 4; it++) {
            int rr = r + it * 16;
            float4 v = *(const float4*)&src[rr * 768 + c4];
            t[rr][c4 + 0] = v.x; t[rr][c4 + 1] = v.y;
            t[rr][c4 + 2] = v.z; t[rr][c4 + 3] = v.w;
        }
        __syncthreads();
        const int k4  = (k0 >> 2) + (tid & 15);
        const int ks  = k4 >> 2;
        const int hb  = (k4 >> 1) & 1;
        const int lhi = k4 & 1;
#pragma unroll
        for (int it = 0; it < 4; it++) {
            int rr  = r + it * 16;
            int col = n0 + rr;
            union { _Float16 h[4]; uint2 u; } c;
#pragma unroll
            for (int kk = 0; kk < 4; kk++) c.h[kk] = (_Float16)t[c4 + kk][rr];
            int off = (((col >> 5) * 16 + ks) << 10) +
                      ((lhi * 32 + (col & 31)) << 4) + hb * 8;
            *(uint2*)((char*)Wfrag + off) = c.u;
        }
    } else {
        // x row-tile (32 rows x 256 k) -> A-fragments (f16)
        const int rt = blk - 560;             // 0..127
        const float* src = x + (size_t)rt * 32 * 256;
        char* dstbase = (char*)xfrag + (size_t)rt * 16384;
#pragma unroll
        for (int it = 0; it < 8; it++) {
            int g   = tid + it * 256;
            int row = g >> 6;
            int k4  = g & 63;
            float4 v = *(const float4*)&src[row * 256 + k4 * 4];
            union { _Float16 h[4]; uint2 u; } c;
            c.h[0] = (_Float16)v.x; c.h[1] = (_Float16)v.y;
            c.h[2] = (_Float16)v.z; c.h[3] = (_Float16)v.w;
            int ks = k4 >> 2, hb = (k4 >> 1) & 1, lhi = k4 & 1;
            int off = (ks << 10) + ((lhi * 32 + row) << 4) + hb * 8;
            *(uint2*)(dstbase + off) = c.u;
        }
    }
}

// ---------------------------------------------------------------------------
// Kernel 2: mid = qkv MFMA GEMM (0..767, frag-direct, XCD-swizzled) +
//           edge kernel (768..1023).
// r19: qkv blocks swizzled swz=(blk&7)*96+(blk>>3) -> XCD k gets all blocks
// of m-rows k*512.. (A-panels 256KB + Wfrag 384KB fit its 4MB L2) [T1].
// ---------------------------------------------------------------------------
__global__ __launch_bounds__(256) void mid_kernel(
    const _Float16* __restrict__ xfrag, const _Float16* __restrict__ Wfrag,
    const float* __restrict__ bias,
    _Float16* __restrict__ Qf, _Float16* __restrict__ Kf,
    _Float16* __restrict__ Vf,
    const float* __restrict__ edge_attr, const int* __restrict__ edge_index,
    const float* __restrict__ adj,
    const float* __restrict__ ds_W, const float* __restrict__ ds_b,
    const float* __restrict__ dw_W, const float* __restrict__ dw_b,
    const float* __restrict__ shifts, const float* __restrict__ widths,
    float* __restrict__ mlog, int* __restrict__ packT)
{
    extern __shared__ char lds[];             // used only by the edge path
    const int tid = threadIdx.x;
    const int blk = blockIdx.x;

    if (blk < 768) {
        // XCD-aware swizzle (bijective on 0..767; 768 = 8*96)
        const int swz = (blk & 7) * 96 + (blk >> 3);
        const int m0 = (swz / 12) * 64;
        const int n0 = (swz % 12) * 64;

        const int wv = tid >> 6, lane = tid & 63, hi = lane >> 5;
        const int rb = wv & 1, cb = wv >> 1;
        const int rbg = (m0 >> 5) + rb;
        const int ctg = (n0 >> 5) + cb;
        const int c_base = n0 + cb * 32;
        const int which  = c_base >> 8;
        const int h      = (c_base >> 5) & 7;
        const int b      = m0 >> 9;
        const int ut     = ((m0 & 511) >> 5) + rb;

        const char* Ap = (const char*)xfrag + ((size_t)rbg << 14);
        const char* Bp = (const char*)Wfrag + ((size_t)ctg << 14);

        f32x16 acc;
#pragma unroll
        for (int r = 0; r < 16; r++) acc[r] = 0.0f;

        if (which < 2) {
            // swapped: C^T, lane owns n-row
#pragma unroll
            for (int ks = 0; ks < 16; ks++) {
                half8 af = *(const half8*)(Bp + (ks << 10) + lane * 16);
                half8 bf = *(const half8*)(Ap + (ks << 10) + lane * 16);
                acc = __builtin_amdgcn_mfma_f32_32x32x16_f16(af, bf, acc, 0, 0, 0);
            }
            _Float16* dst = (which == 0) ? Qf : Kf;
            const float sc = (which == 0) ? SCALE : 1.0f;
            size_t pb = (((size_t)(b * H_ + h) * 16 + ut) * 2) * 1024;
#pragma unroll
            for (int kh = 0; kh < 2; kh++) {
                union { _Float16 h[8]; int4 q; } fr;
#pragma unroll
                for (int j = 0; j < 8; j++) {
                    int r = kh * 8 + j;
                    int hd = (r & 3) + 8 * (r >> 2) + 4 * hi;
                    fr.h[j] = (_Float16)((acc[r] + bias[c_base + hd]) * sc);
                }
                *(int4*)((char*)dst + pb + kh * 1024 + lane * 16) = fr.q;
            }
        } else {
            // normal: lane owns hd-col
#pragma unroll
            for (int ks = 0; ks < 16; ks++) {
                half8 af = *(const half8*)(Ap + (ks << 10) + lane * 16);
                half8 bf = *(const half8*)(Bp + (ks << 10) + lane * 16);
                acc = __builtin_amdgcn_mfma_f32_32x32x16_f16(af, bf, acc, 0, 0, 0);
            }
            const float bcol = bias[c_base + (lane & 31)];
            size_t pb = (((size_t)(b * H_ + h) * 16 + ut) * 2) * 1024;
#pragma unroll
            for (int kh = 0; kh < 2; kh++) {
                union { _Float16 h[8]; int4 q; } fr;
#pragma unroll
                for (int j = 0; j < 8; j++)
                    fr.h[j] = (_Float16)(acc[kh * 8 + j] + bcol);
                *(int4*)((char*)Vf + pb + kh * 1024 + lane * 16) = fr.q;
            }
        }
        return;
    }

    // ---------------- edge kernel (unchanged, r15-verified) ----------------
    float* ea  = (float*)lds;
    float* dsW = ea + 256 * 33;
    float* dwW = dsW + 256;
    const int eb = blk - 768;
    const int b  = eb >> 5;
    const int e0 = (eb & 31) * 256;

    const float* eabase = edge_attr + ((size_t)b * E_ + e0) * EA_;
#pragma unroll
    for (int it = 0; it < 32; it++) {
        int i = tid + it * 256;
        ea[(i >> 5) * 33 + (i & 31)] = eabase[i];
    }
    dsW[tid] = ds_W[tid];
    dwW[tid] = dw_W[tid];
    __syncthreads();

    const int e  = e0 + tid;
    const int eu = edge_index[(size_t)b * 2 * E_ + e];
    const int ev = edge_index[(size_t)b * 2 * E_ + E_ + e];
    const float d = adj[((size_t)b * N_ + eu) * N_ + ev];

    float ds[8], dw[8];
#pragma unroll
    for (int h = 0; h < 8; h++) { ds[h] = ds_b[h]; dw[h] = dw_b[h]; }
#pragma unroll
    for (int k = 0; k < 32; k++) {
        float a = ea[tid * 33 + k];
#pragma unroll
        for (int h = 0; h < 8; h++) {
            ds[h] += a * dsW[k * 8 + h];
            dw[h] += a * dwW[k * 8 + h];
        }
    }
#pragma unroll
    for (int h = 0; h < 8; h++) {
        float ms = shifts[h] + ds[h];
        float mw = widths[h] + dw[h];
        float t  = d - ms;
        float ml = fmaxf(-(t * t) / (2.0f * mw * mw + 1e-6f), LOG1EM6);
        mlog[((size_t)(b * H_ + h)) * E_ + e] = ml;
    }
    union { _Float16 f; unsigned short s; } ab;
    ab.f = (_Float16)d;                       // same conversion as prep
    atomicMax(&packT[((size_t)b * N_ + ev) * N_ + eu],
              (((int)ab.s) << 16) | (e + 1));
}

// ---------------------------------------------------------------------------
// helpers
// ---------------------------------------------------------------------------
__device__ __forceinline__ unsigned pkf16(float x, float y)
{
    fp16x2 v = __builtin_amdgcn_cvt_pkrtz(x, y);
    union { fp16x2 h; unsigned u; } c; c.h = v; return c.u;
}

__device__ __forceinline__ half8 pack_pfrag(const float* p)
{
    union { unsigned u[4]; half8 h; } r;
    r.u[0] = pkf16(p[0], p[1]);
    r.u[1] = pkf16(p[2], p[3]);
    r.u[2] = pkf16(p[4], p[5]);
    r.u[3] = pkf16(p[6], p[7]);
    return r.h;
}

__device__ __forceinline__ float av_from_pack(int pk)
{
    union { unsigned short s; _Float16 f; } cc;
    cc.s = (unsigned short)(((unsigned)pk) >> 16);
    return (float)cc.f;
}

// ---------------------------------------------------------------------------
// Kernel 3: MFMA attention, 8-way flash v-split (r17-verified) +
// r19 XCD swizzle: swz=(bid&7)*128+(bid>>3) -> XCD k gets all 128 blocks of
// batch k; its packT (1MB) + K/V/Q panels (768KB) + mlog (256KB) fit the
// per-XCD 4MB L2 [T1].
// ---------------------------------------------------------------------------
__global__ __launch_bounds__(512) void attn_kernel(
    const _Float16* __restrict__ Qf, const _Float16* __restrict__ Kf,
    const _Float16* __restrict__ Vf, const int* __restrict__ packT,
    const float* __restrict__ mlog,
    const float* __restrict__ shifts, const float* __restrict__ widths,
    const float* __restrict__ slw_arr, float* __restrict__ out)
{
    __shared__ float ldsO[8][16][64];
    __shared__ float ldsM[8][64];
    __shared__ float ldsS[8][64];

    // XCD-aware swizzle (bijective on 0..1023; 1024 = 8*128)
    const int bid  = (blockIdx.x & 7) * 128 + (blockIdx.x >> 3);
    const int b    = bid >> 7;
    const int h    = (bid >> 4) & 7;
    const int ut   = bid & 15;
    const int wv   = threadIdx.x >> 6;    // v-split id 0..7
    const int lane = threadIdx.x & 63;
    const int hi   = lane >> 5;
    const int u0w  = ut * 32;

    const size_t panel = ((size_t)(b * H_ + h) * 16) * 2048; // bytes
    const char* Kp = (const char*)Kf + panel;
    const char* Vp = (const char*)Vf + panel;
    const char* Qp = (const char*)Qf + panel;

    half8 qf0 = *(const half8*)(Qp + (ut * 2 + 0) * 1024 + lane * 16);
    half8 qf1 = *(const half8*)(Qp + (ut * 2 + 1) * 1024 + lane * 16);

    const float s_h   = shifts[h];
    const float w_h   = widths[h];
    const float inv2w = 1.0f / (2.0f * w_h * w_h + 1e-6f);
    const float slw   = slw_arr[h];
    const float* mlg  = mlog + (size_t)(b * H_ + h) * E_;
    const int ucol    = u0w + (lane & 31);
    const int* prow   = packT + (size_t)b * N_ * N_ + ucol;

    f32x16 Oacc;
#pragma unroll
    for (int r = 0; r < 16; r++) Oacc[r] = 0.0f;
    float m = -1e30f, ssum = 0.0f;

#pragma unroll
    for (int i = 0; i < 2; i++) {
        const int vt = wv * 2 + i;
        half8 ka0 = *(const half8*)(Kp + (vt * 2 + 0) * 1024 + lane * 16);
        half8 ka1 = *(const half8*)(Kp + (vt * 2 + 1) * 1024 + lane * 16);
        f32x16 C;
#pragma unroll
        for (int r = 0; r < 16; r++) C[r] = 0.0f;
        C = __builtin_amdgcn_mfma_f32_32x32x16_f16(ka0, qf0, C, 0, 0, 0);
        C = __builtin_amdgcn_mfma_f32_32x32x16_f16(ka1, qf1, C, 0, 0, 0);

        float p[16];
        float pmax = -1e30f;
        const int vbase = vt * 32 + 4 * hi;
#pragma unroll
        for (int r = 0; r < 16; r++) {
            int vg  = vbase + (r & 3) + 8 * (r >> 2);
            int pkr = prow[(size_t)vg * N_];
            int sv  = (pkr & 0xffff) - 1;
            float av = av_from_pack(pkr);
            float ml = mlg[sv < 0 ? 0 : sv];
            float t  = av - s_h;
            float bl = fmaxf(-(t * t) * inv2w, LOG1EM6);
            float sc = C[r] + (sv >= 0 ? ml : bl);
            if (vg == ucol) sc += slw;
            p[r] = sc;
            pmax = fmaxf(pmax, sc);
        }
        pmax = fmaxf(pmax, __shfl_xor(pmax, 32, 64));

        if (!__all(pmax - m <= 8.0f)) {
            float mnew = fmaxf(m, pmax);
            float scl  = __expf(m - mnew);
#pragma unroll
            for (int r = 0; r < 16; r++) {
                int ur = (r & 3) + 8 * (r >> 2) + 4 * hi;
                Oacc[r] *= __shfl(scl, ur, 64);
            }
            ssum *= scl;
            m = mnew;
        }

#pragma unroll
        for (int r = 0; r < 16; r++) {
            p[r] = __expf(p[r] - m);
            ssum += p[r];
        }

        half8 pa0 = pack_pfrag(&p[0]);
        half8 pa1 = pack_pfrag(&p[8]);
        half8 vb0 = *(const half8*)(Vp + (vt * 2 + 0) * 1024 + lane * 16);
        half8 vb1 = *(const half8*)(Vp + (vt * 2 + 1) * 1024 + lane * 16);
        Oacc = __builtin_amdgcn_mfma_f32_32x32x16_f16(pa0, vb0, Oacc, 0, 0, 0);
        Oacc = __builtin_amdgcn_mfma_f32_32x32x16_f16(pa1, vb1, Oacc, 0, 0, 0);
    }

#pragma unroll
    for (int r = 0; r < 16; r++) ldsO[wv][r][lane] = Oacc[r];
    ldsM[wv][lane] = m;
    ldsS[wv][lane] = ssum;
    __syncthreads();

    float ms_[8], ss_[8];
#pragma unroll
    for (int s = 0; s < 8; s++) { ms_[s] = ldsM[s][lane]; ss_[s] = ldsS[s][lane]; }
    float mt = ms_[0];
#pragma unroll
    for (int s = 1; s < 8; s++) mt = fmaxf(mt, ms_[s]);
    float scs[8];
    float denom = 0.0f;
#pragma unroll
    for (int s = 0; s < 8; s++) {
        scs[s] = __expf(ms_[s] - mt);
        denom += ss_[s] * scs[s];
    }
    float stot = denom + __shfl_xor(denom, 32, 64);
    float rs = 1.0f / stot;

#pragma unroll
    for (int rr = 0; rr < 2; rr++) {
        int r  = wv * 2 + rr;
        int ur = (r & 3) + 8 * (r >> 2) + 4 * hi;
        float o = 0.0f;
#pragma unroll
        for (int s = 0; s < 8; s++)
            o += ldsO[s][r][lane] * __shfl(scs[s], ur, 64);
        o *= __shfl(rs, ur, 64);
        int ug = u0w + ur;
        out[((size_t)(b * N_ + ug)) * D_ + h * HD_ + (lane & 31)] = o;
    }
}

// ---------------------------------------------------------------------------
extern "C" void kernel_launch(void* const* d_in, const int* in_sizes, int n_in,
                              void* d_out, int out_size, void* d_ws, size_t ws_size,
                              hipStream_t stream)
{
    const float* x          = (const float*)d_in[0];
    const float* adj        = (const float*)d_in[1];
    const int*   edge_index = (const int*)d_in[2];
    const float* edge_attr  = (const float*)d_in[3];
    const float* qkv_W      = (const float*)d_in[6];
    const float* qkv_b      = (const float*)d_in[7];
    const float* ds_W       = (const float*)d_in[12];
    const float* ds_b       = (const float*)d_in[13];
    const float* dw_W       = (const float*)d_in[14];
    const float* dw_b       = (const float*)d_in[15];
    const float* shifts     = (const float*)d_in[16];
    const float* widths     = (const float*)d_in[17];
    const float* slw        = (const float*)d_in[18];
    float* out = (float*)d_out;

    // workspace layout (~18.4MB)
    _Float16* Qf    = (_Float16*)d_ws;                     // 2MB
    _Float16* Kf    = Qf + (size_t)B_ * H_ * N_ * HD_;     // 2MB
    _Float16* Vf    = Kf + (size_t)B_ * H_ * N_ * HD_;     // 2MB
    float*    mlog  = (float*)(Vf + (size_t)B_ * H_ * N_ * HD_);   // 2MB
    int*      packT = (int*)(mlog + (size_t)B_ * H_ * E_); // 8MB
    _Float16* xfrag = (_Float16*)(packT + (size_t)B_ * N_ * N_);   // 2MB
    _Float16* Wfrag = xfrag + (size_t)B_ * N_ * D_;        // 384KB

    prep_kernel<<<dim3(688), 256, 0, stream>>>(packT, qkv_W, Wfrag, adj,
                                               x, xfrag);

    hipFuncSetAttribute((const void*)mid_kernel,
                        hipFuncAttributeMaxDynamicSharedMemorySize, 65536);
    mid_kernel<<<dim3(1024), 256, 65536, stream>>>(
        xfrag, Wfrag, qkv_b, Qf, Kf, Vf,
        edge_attr, edge_index, adj,
        ds_W, ds_b, dw_W, dw_b, shifts, widths, mlog, packT);

    attn_kernel<<<dim3(1024), 512, 0, stream>>>(Qf, Kf, Vf, packT,
                                                mlog, shifts, widths, slw, out);
}